// Round 2
// baseline (1207.309 us; speedup 1.0000x reference)
//
#include <hip/hip_runtime.h>

#define NNODES 50000
#define NPAD   50048   // 391 * 128
#define NEDGES 800000
#define HDIM 128
#define OUTDIM 64

#define GEMM_GRID 391
#define GEMM_BLK  512
#define GEMM_TILES (NPAD / 16)  // 3128 = 391 * 8 : exactly 1 tile per wave

#define DBUCKETS 512

typedef short short8 __attribute__((ext_vector_type(8)));
typedef _Float16 half8 __attribute__((ext_vector_type(8)));
typedef _Float16 half4 __attribute__((ext_vector_type(4)));
typedef float f32x4 __attribute__((ext_vector_type(4)));
typedef float f32x8 __attribute__((ext_vector_type(8)));

__device__ __forceinline__ unsigned short f2bf(float f) {
    unsigned int u = __builtin_bit_cast(unsigned int, f);
    unsigned int r = (u + 0x7FFFu + ((u >> 16) & 1u)) >> 16;
    return (unsigned short)r;
}
__device__ __forceinline__ float bf2f(unsigned short b) {
    unsigned int u = ((unsigned int)b) << 16;
    return __builtin_bit_cast(float, u);
}

// ---------------- CSR build ----------------
__global__ void count_kernel(const int* __restrict__ dst, int* __restrict__ deg,
                             int* __restrict__ epos) {
    int e = blockIdx.x * 256 + threadIdx.x;
    if (e < NEDGES) epos[e] = atomicAdd(&deg[dst[e]], 1);
}

__global__ __launch_bounds__(256) void bsum_kernel(const int* __restrict__ deg,
                                                   int* __restrict__ bsum) {
    __shared__ int red[256];
    int i = blockIdx.x * 256 + threadIdx.x;
    red[threadIdx.x] = (i < NNODES) ? deg[i] : 0;
    __syncthreads();
    for (int off = 128; off; off >>= 1) {
        if (threadIdx.x < off) red[threadIdx.x] += red[threadIdx.x + off];
        __syncthreads();
    }
    if (threadIdx.x == 0) bsum[blockIdx.x] = red[0];
}

__global__ __launch_bounds__(256) void bscan_kernel(const int* __restrict__ bsum,
                                                    int* __restrict__ bofs) {
    __shared__ int s[256];
    int t = threadIdx.x;
    int v = (t < 196) ? bsum[t] : 0;
    s[t] = v;
    __syncthreads();
    for (int off = 1; off < 256; off <<= 1) {
        int u = (t >= off) ? s[t - off] : 0;
        __syncthreads();
        s[t] += u;
        __syncthreads();
    }
    if (t < 196) bofs[t] = s[t] - v;  // exclusive
}

__global__ __launch_bounds__(256) void emit_kernel(
    const int* __restrict__ deg, const int* __restrict__ bofs,
    int* __restrict__ row_ptr, float* __restrict__ norm) {
    __shared__ int s[256];
    int t = threadIdx.x;
    int i = blockIdx.x * 256 + t;
    int v = (i < NNODES) ? deg[i] : 0;
    s[t] = v;
    __syncthreads();
    for (int off = 1; off < 256; off <<= 1) {
        int u = (t >= off) ? s[t - off] : 0;
        __syncthreads();
        s[t] += u;
        __syncthreads();
    }
    int excl = s[t] - v + bofs[blockIdx.x];
    if (i < NNODES) {
        row_ptr[i] = excl;
        norm[i] = rsqrtf(1.0f + (float)v);
    }
    if (i == NNODES - 1) row_ptr[NNODES] = NEDGES;
}

__global__ void fill_kernel(const int* __restrict__ src, const int* __restrict__ dst,
                            const int* __restrict__ epos, const int* __restrict__ row_ptr,
                            int* __restrict__ sorted_src) {
    int e = blockIdx.x * 256 + threadIdx.x;
    if (e < NEDGES) sorted_src[row_ptr[dst[e]] + epos[e]] = src[e];
}

// ---------------- degree-sorted node permutation (gather load balance) ------
__global__ void dhist_kernel(const int* __restrict__ deg, int* __restrict__ dcount) {
    int i = blockIdx.x * 256 + threadIdx.x;
    if (i < NNODES) atomicAdd(&dcount[min(deg[i], DBUCKETS - 1)], 1);
}

__global__ __launch_bounds__(DBUCKETS) void dscan_kernel(const int* __restrict__ dcount,
                                                         int* __restrict__ dofs) {
    __shared__ int s[DBUCKETS];
    int t = threadIdx.x;
    int v = dcount[t];
    s[t] = v;
    __syncthreads();
    for (int off = 1; off < DBUCKETS; off <<= 1) {
        int u = (t >= off) ? s[t - off] : 0;
        __syncthreads();
        s[t] += u;
        __syncthreads();
    }
    dofs[t] = s[t] - v;  // exclusive
}

__global__ void dscatter_kernel(const int* __restrict__ deg, int* __restrict__ dfill,
                                const int* __restrict__ dofs, int* __restrict__ perm) {
    int i = blockIdx.x * 256 + threadIdx.x;
    if (i < NNODES) {
        int b = min(deg[i], DBUCKETS - 1);
        int pos = dofs[b] + atomicAdd(&dfill[b], 1);
        perm[pos] = i;
    }
}

// ---------------- weight prep ----------------
// bf16 hi/lo (wT): w_in slot 0, w1[m] slot 1+m, w_out slot 7 (64 rows).
// f16 single (w2f): w2[m] at m*16384, layout [n][128].
__global__ __launch_bounds__(256) void prep_w_kernel(
    const float* __restrict__ w_in, const float* __restrict__ w1,
    const float* __restrict__ w2, const float* __restrict__ w_out,
    unsigned short* __restrict__ wT, _Float16* __restrict__ w2f) {
    int idx = blockIdx.x * 256 + threadIdx.x;  // total 221184 = 864*256
    if (idx < 16384 + 98304) {
        const float* W;
        unsigned short* o;
        int e;
        if (idx < 16384) {
            W = w_in; o = wT; e = idx;
        } else {
            int j = idx - 16384; int m = j >> 14; e = j & 16383;
            W = w1 + ((size_t)m << 14); o = wT + (size_t)(1 + m) * 32768;
        }
        int k = e >> 7, n = e & 127;
        float v = W[e];
        unsigned short h = f2bf(v);
        o[(size_t)n * 256 + k] = h;
        o[(size_t)n * 256 + 128 + k] = f2bf(v - bf2f(h));
    } else if (idx < 16384 + 196608) {
        int j = idx - 16384 - 98304; int m = j >> 14; int e = j & 16383;
        int k = e >> 7, n = e & 127;
        w2f[(size_t)m * 16384 + n * 128 + k] = (_Float16)w2[((size_t)m << 14) + e];
    } else {
        int e = idx - 212992;  // w_out: 8192 elements
        int k = e >> 6, n = e & 63;
        float v = w_out[e];
        unsigned short h = f2bf(v);
        unsigned short* o = wT + (size_t)7 * 32768;
        o[(size_t)n * 256 + k] = h;
        o[(size_t)n * 256 + 128 + k] = f2bf(v - bf2f(h));
    }
}

// ---------------- x split (input layer only) ----------------
__global__ __launch_bounds__(256) void split_x_kernel(
    const float* __restrict__ x, unsigned short* __restrict__ xc) {
    int gid = blockIdx.x * 256 + threadIdx.x;
    int row = gid >> 6;
    int kk = (gid & 63) * 2;
    float2 v = {0.f, 0.f};
    if (row < NNODES) v = *(const float2*)(x + (size_t)row * 128 + kk);
    unsigned short h0 = f2bf(v.x), h1 = f2bf(v.y);
    unsigned short l0 = f2bf(v.x - bf2f(h0)), l1 = f2bf(v.y - bf2f(h1));
    *(unsigned int*)(xc + (size_t)row * 256 + kk) =
        (unsigned int)h0 | ((unsigned int)h1 << 16);
    *(unsigned int*)(xc + (size_t)row * 256 + 128 + kk) =
        (unsigned int)l0 | ((unsigned int)l1 << 16);
}

// ---------------- bf16 hi/lo streaming MFMA GEMM ----------------
// Whole B (hi+lo) staged once into LDS (chunk-level XOR swizzle); single
// barrier; 1 output tile (16 rows) per wave, grid*waves == tiles exactly.
template <int NCOLS>
__global__ __launch_bounds__(GEMM_BLK) void gemm_bf_kernel(
    const unsigned short* __restrict__ xc, const unsigned short* __restrict__ wT,
    const float* __restrict__ norm, _Float16* __restrict__ y) {
    __shared__ unsigned short Blds[NCOLS * 256];
    const int t = threadIdx.x;
    const int wave = t >> 6, lane = t & 63, quad = lane >> 4, l16 = lane & 15;

    constexpr int NCH = NCOLS * 32;  // 16B chunks total
#pragma unroll
    for (int i = 0; i < NCH / GEMM_BLK; ++i) {
        int C = i * GEMM_BLK + t;
        int n = C >> 5, c = C & 31;
        const unsigned short* gp = wT + ((size_t)n << 8) + ((c ^ (n & 7)) << 3);
        unsigned short* lp = Blds + ((size_t)C << 3);
        __builtin_amdgcn_global_load_lds(
            (const __attribute__((address_space(1))) void*)gp,
            (__attribute__((address_space(3))) void*)lp, 16, 0, 0);
    }
    __syncthreads();

    const int wid = blockIdx.x * (GEMM_BLK / 64) + wave;
    const int sw = l16 & 7;
    const int rb0 = wid * 16;

    short8 a0[8];
    const unsigned short* ap0 = xc + ((size_t)(rb0 + l16) << 8) + quad * 8;
#pragma unroll
    for (int ck = 0; ck < 8; ++ck) a0[ck] = *(const short8*)(ap0 + ck * 32);

    float nm0[4];
#pragma unroll
    for (int r = 0; r < 4; ++r) {
        int r0 = rb0 + quad * 4 + r;
        nm0[r] = norm[r0 < NNODES ? r0 : 0];
    }

#pragma unroll
    for (int nt = 0; nt < NCOLS / 16; ++nt) {
        const unsigned short* bp = Blds + ((size_t)(nt * 16 + l16) << 8);
        short8 bh[4], bl[4];
#pragma unroll
        for (int ck = 0; ck < 4; ++ck) {
            bh[ck] = *(const short8*)(bp + (((ck * 4 + quad) ^ sw) << 3));
            bl[ck] = *(const short8*)(bp + (((16 + ck * 4 + quad) ^ sw) << 3));
        }
        f32x4 ac0 = (f32x4){0.f, 0.f, 0.f, 0.f};
#pragma unroll
        for (int ck = 0; ck < 4; ++ck) {
            ac0 = __builtin_amdgcn_mfma_f32_16x16x32_bf16(a0[ck], bh[ck], ac0, 0, 0, 0);
            ac0 = __builtin_amdgcn_mfma_f32_16x16x32_bf16(a0[ck], bl[ck], ac0, 0, 0, 0);
            ac0 = __builtin_amdgcn_mfma_f32_16x16x32_bf16(a0[4 + ck], bh[ck], ac0, 0, 0, 0);
        }
        int col = nt * 16 + l16;
#pragma unroll
        for (int r = 0; r < 4; ++r) {
            int r0 = rb0 + quad * 4 + r;
            if (r0 < NNODES) y[(size_t)r0 * NCOLS + col] = (_Float16)(ac0[r] * nm0[r]);
        }
    }
}

// ---------------- f16 streaming MFMA GEMM (x-conv) ----------------
__global__ __launch_bounds__(GEMM_BLK) void gemm_f16_kernel(
    const _Float16* __restrict__ A, const _Float16* __restrict__ wf,
    const float* __restrict__ norm, _Float16* __restrict__ y) {
    __shared__ _Float16 Blds[128 * 128];
    const int t = threadIdx.x;
    const int wave = t >> 6, lane = t & 63, quad = lane >> 4, l16 = lane & 15;

#pragma unroll
    for (int i = 0; i < 2048 / GEMM_BLK; ++i) {  // 128 rows x 16 chunks
        int C = i * GEMM_BLK + t;
        int n = C >> 4, c = C & 15;
        const _Float16* gp = wf + ((size_t)n << 7) + ((c ^ (n & 7)) << 3);
        _Float16* lp = Blds + ((size_t)C << 3);
        __builtin_amdgcn_global_load_lds(
            (const __attribute__((address_space(1))) void*)gp,
            (__attribute__((address_space(3))) void*)lp, 16, 0, 0);
    }
    __syncthreads();

    const int wid = blockIdx.x * (GEMM_BLK / 64) + wave;
    const int sw = l16 & 7;
    const int rb0 = wid * 16;

    half8 a0[4];
    const _Float16* ap0 = A + ((size_t)(rb0 + l16) << 7) + quad * 8;
#pragma unroll
    for (int ck = 0; ck < 4; ++ck) a0[ck] = *(const half8*)(ap0 + ck * 32);

    float nm0[4];
#pragma unroll
    for (int r = 0; r < 4; ++r) {
        int r0 = rb0 + quad * 4 + r;
        nm0[r] = norm[r0 < NNODES ? r0 : 0];
    }

#pragma unroll
    for (int nt = 0; nt < 8; ++nt) {
        const _Float16* bp = Blds + ((size_t)(nt * 16 + l16) << 7);
        half8 b[4];
#pragma unroll
        for (int ck = 0; ck < 4; ++ck)
            b[ck] = *(const half8*)(bp + (((ck * 4 + quad) ^ sw) << 3));
        f32x4 ac0 = (f32x4){0.f, 0.f, 0.f, 0.f};
#pragma unroll
        for (int ck = 0; ck < 4; ++ck)
            ac0 = __builtin_amdgcn_mfma_f32_16x16x32_f16(a0[ck], b[ck], ac0, 0, 0, 0);
        int col = nt * 16 + l16;
#pragma unroll
        for (int r = 0; r < 4; ++r) {
            int r0 = rb0 + quad * 4 + r;
            if (r0 < NNODES) y[(size_t)r0 * 128 + col] = (_Float16)(ac0[r] * nm0[r]);
        }
    }
}

// ---------------- fused gather + finalize (F=128, fp16 y) ----------------
// Nodes processed in degree-sorted order (perm) so the 4 nodes sharing a
// wave have near-equal degree (dmax ~= deg, no wasted slots).
// 16 lanes per node, 16B per lane; 8-deep unroll = 32 rows in flight/wave.
template <int MODE, bool WOUT, bool OUT16>
__global__ __launch_bounds__(256) void gather_fin128(
    const _Float16* __restrict__ y, const int* __restrict__ row_ptr,
    const int* __restrict__ sorted_src, const float* __restrict__ norm,
    const float* __restrict__ bias, const unsigned short* __restrict__ xcres,
    float* __restrict__ out, unsigned short* __restrict__ xcout,
    _Float16* __restrict__ h16, const int* __restrict__ perm) {
    const int wave = threadIdx.x >> 6;
    const int lane = threadIdx.x & 63;
    const int g = lane >> 4, j = lane & 15;
    const int n = perm[blockIdx.x * 16 + wave * 4 + g];
    const int beg = row_ptr[n];
    const int deg = row_ptr[n + 1] - beg;
    int dmax = deg;
    dmax = max(dmax, __shfl_xor(dmax, 16));
    dmax = max(dmax, __shfl_xor(dmax, 32));

    f32x8 acc = (f32x8){0.f, 0.f, 0.f, 0.f, 0.f, 0.f, 0.f, 0.f};

    for (int i = 0; i < dmax; i += 8) {
        int sarr[8];
#pragma unroll
        for (int u = 0; u < 8; ++u)
            sarr[u] = (i + u < deg) ? sorted_src[beg + i + u] : -1;
        half8 h[8];
#pragma unroll
        for (int u = 0; u < 8; ++u)
            if (sarr[u] >= 0)
                h[u] = *(const half8*)(y + ((size_t)sarr[u] << 7) + j * 8);
#pragma unroll
        for (int u = 0; u < 8; ++u)
            if (sarr[u] >= 0) acc += __builtin_convertvector(h[u], f32x8);
    }

    const half8 sh = *(const half8*)(y + ((size_t)n << 7) + j * 8);
    const float4 b0 = *(const float4*)(bias + j * 8);
    const float4 b1 = *(const float4*)(bias + j * 8 + 4);
    const float bb[8] = {b0.x, b0.y, b0.z, b0.w, b1.x, b1.y, b1.z, b1.w};
    const float nm = norm[n];
    float v[8];
#pragma unroll
    for (int c = 0; c < 8; ++c) {
        float t = (acc[c] + (float)sh[c]) * nm + bb[c];
        v[c] = t >= 0.f ? t : 0.01f * t;
    }
    if (MODE == 1) {
        short8 hw = *(const short8*)(xcres + ((size_t)n << 8) + j * 8);
        short8 lw = *(const short8*)(xcres + ((size_t)n << 8) + 128 + j * 8);
#pragma unroll
        for (int c = 0; c < 8; ++c) {
            float xr = bf2f((unsigned short)hw[c]) + bf2f((unsigned short)lw[c]);
            v[c] = (xr + v[c]) * 0.5f;
        }
    }
    if (WOUT) {
        float4 o0 = {v[0], v[1], v[2], v[3]};
        float4 o1 = {v[4], v[5], v[6], v[7]};
        *(float4*)(out + ((size_t)n << 7) + j * 8) = o0;
        *(float4*)(out + ((size_t)n << 7) + j * 8 + 4) = o1;
    }
    if (OUT16) {
        half8 o;
#pragma unroll
        for (int c = 0; c < 8; ++c) o[c] = (_Float16)v[c];
        *(half8*)(h16 + ((size_t)n << 7) + j * 8) = o;
    } else {
        short8 hi, lo;
#pragma unroll
        for (int c = 0; c < 8; ++c) {
            unsigned short hv = f2bf(v[c]);
            hi[c] = (short)hv;
            lo[c] = (short)f2bf(v[c] - bf2f(hv));
        }
        *(short8*)(xcout + ((size_t)n << 8) + j * 8) = hi;
        *(short8*)(xcout + ((size_t)n << 8) + 128 + j * 8) = lo;
    }
}

// ---------------- final gather (F=64, identity, fp16 y) ----------------
__global__ __launch_bounds__(256) void gather_fin64(
    const _Float16* __restrict__ y, const int* __restrict__ row_ptr,
    const int* __restrict__ sorted_src, const float* __restrict__ norm,
    const float* __restrict__ bias, float* __restrict__ out,
    const int* __restrict__ perm) {
    const int wave = threadIdx.x >> 6;
    const int lane = threadIdx.x & 63;
    const int g = lane >> 4, j = lane & 15;
    const int n = perm[blockIdx.x * 16 + wave * 4 + g];
    const int beg = row_ptr[n];
    const int deg = row_ptr[n + 1] - beg;
    int dmax = deg;
    dmax = max(dmax, __shfl_xor(dmax, 16));
    dmax = max(dmax, __shfl_xor(dmax, 32));

    f32x4 acc = (f32x4){0.f, 0.f, 0.f, 0.f};
    for (int i = 0; i < dmax; i += 8) {
        int sarr[8];
#pragma unroll
        for (int u = 0; u < 8; ++u)
            sarr[u] = (i + u < deg) ? sorted_src[beg + i + u] : -1;
        half4 h[8];
#pragma unroll
        for (int u = 0; u < 8; ++u)
            if (sarr[u] >= 0)
                h[u] = *(const half4*)(y + ((size_t)sarr[u] << 6) + j * 4);
#pragma unroll
        for (int u = 0; u < 8; ++u)
            if (sarr[u] >= 0) acc += __builtin_convertvector(h[u], f32x4);
    }

    const half4 sh = *(const half4*)(y + ((size_t)n << 6) + j * 4);
    const float4 b = *(const float4*)(bias + j * 4);
    const float bb[4] = {b.x, b.y, b.z, b.w};
    const float nm = norm[n];
    float4 o;
    o.x = (acc[0] + (float)sh[0]) * nm + bb[0];
    o.y = (acc[1] + (float)sh[1]) * nm + bb[1];
    o.z = (acc[2] + (float)sh[2]) * nm + bb[2];
    o.w = (acc[3] + (float)sh[3]) * nm + bb[3];
    *(float4*)(out + ((size_t)n << 6) + j * 4) = o;
}

extern "C" void kernel_launch(void* const* d_in, const int* in_sizes, int n_in,
                              void* d_out, int out_size, void* d_ws, size_t ws_size,
                              hipStream_t stream) {
    const float* inputs = (const float*)d_in[0];
    const int* edges = (const int*)d_in[1];
    const int* src = edges;
    const int* dst = edges + NEDGES;
    const float* w_in  = (const float*)d_in[2];
    const float* b_in  = (const float*)d_in[3];
    const float* w1    = (const float*)d_in[4];
    const float* b1    = (const float*)d_in[5];
    const float* w2    = (const float*)d_in[6];
    const float* b2    = (const float*)d_in[7];
    const float* w_out = (const float*)d_in[8];
    const float* b_out = (const float*)d_in[9];

    float* out  = (float*)d_out;
    float* xout = out;                                // [N, 64]
    float* x    = out + (size_t)NNODES * OUTDIM;      // [N, 128] fp32 x (final only)

    char* p = (char*)d_ws;
    auto alloc = [&](size_t bytes) {
        char* r = p;
        p += (bytes + 63) & ~(size_t)63;
        return r;
    };
    int* deg        = (int*)alloc(NNODES * 4);
    int* epos       = (int*)alloc(NEDGES * 4);
    int* row_ptr    = (int*)alloc((NNODES + 1) * 4);
    int* bsum       = (int*)alloc(256 * 4);
    int* bofs       = (int*)alloc(256 * 4);
    int* sorted_src = (int*)alloc(NEDGES * 4);
    float* normb    = (float*)alloc(NNODES * 4);
    int* dctr       = (int*)alloc(2 * DBUCKETS * 4);   // dcount | dfill
    int* dofs       = (int*)alloc(DBUCKETS * 4);
    int* perm       = (int*)alloc(NNODES * 4);
    unsigned short* wT = (unsigned short*)alloc((size_t)245760 * 2);  // 7*32768+16384
    _Float16* w2f   = (_Float16*)alloc((size_t)6 * 16384 * 2);
    unsigned short* xc_x = (unsigned short*)alloc((size_t)NPAD * 256 * 2);
    unsigned short* xc_in = (unsigned short*)alloc((size_t)NPAD * 256 * 2);
    _Float16* h16   = (_Float16*)alloc((size_t)NPAD * 128 * 2);
    _Float16* y     = (_Float16*)alloc((size_t)NNODES * HDIM * 2);

    int* dcount = dctr;
    int* dfill  = dctr + DBUCKETS;

    // ---- CSR + norm + degree-sorted perm + weight prep ----
    hipMemsetAsync(deg, 0, NNODES * sizeof(int), stream);
    hipMemsetAsync(dctr, 0, 2 * DBUCKETS * sizeof(int), stream);
    count_kernel<<<(NEDGES + 255) / 256, 256, 0, stream>>>(dst, deg, epos);
    dhist_kernel<<<(NNODES + 255) / 256, 256, 0, stream>>>(deg, dcount);
    dscan_kernel<<<1, DBUCKETS, 0, stream>>>(dcount, dofs);
    dscatter_kernel<<<(NNODES + 255) / 256, 256, 0, stream>>>(deg, dfill, dofs, perm);
    bsum_kernel<<<196, 256, 0, stream>>>(deg, bsum);
    bscan_kernel<<<1, 256, 0, stream>>>(bsum, bofs);
    emit_kernel<<<196, 256, 0, stream>>>(deg, bofs, row_ptr, normb);
    fill_kernel<<<(NEDGES + 255) / 256, 256, 0, stream>>>(src, dst, epos, row_ptr, sorted_src);
    prep_w_kernel<<<864, 256, 0, stream>>>(w_in, w1, w2, w_out, wT, w2f);

    // input layer
    split_x_kernel<<<(NPAD * 64) / 256, 256, 0, stream>>>(inputs, xc_in);
    gemm_bf_kernel<128><<<GEMM_GRID, GEMM_BLK, 0, stream>>>(xc_in, wT, normb, y);
    gather_fin128<0, false, false><<<NNODES / 16, 256, 0, stream>>>(
        y, row_ptr, sorted_src, normb, b_in, nullptr, nullptr, xc_x, nullptr, perm);

    // 6 residual blocks
    for (int i = 0; i < 6; ++i) {
        gemm_bf_kernel<128><<<GEMM_GRID, GEMM_BLK, 0, stream>>>(
            xc_x, wT + (size_t)(1 + i) * 32768, normb, y);
        gather_fin128<0, false, true><<<NNODES / 16, 256, 0, stream>>>(
            y, row_ptr, sorted_src, normb, b1 + i * HDIM, nullptr, nullptr, nullptr, h16, perm);
        gemm_f16_kernel<<<GEMM_GRID, GEMM_BLK, 0, stream>>>(
            h16, w2f + (size_t)i * 16384, normb, y);
        if (i < 5)
            gather_fin128<1, false, false><<<NNODES / 16, 256, 0, stream>>>(
                y, row_ptr, sorted_src, normb, b2 + i * HDIM, xc_x, nullptr, xc_x, nullptr, perm);
        else
            gather_fin128<1, true, false><<<NNODES / 16, 256, 0, stream>>>(
                y, row_ptr, sorted_src, normb, b2 + i * HDIM, xc_x, x, xc_x, nullptr, perm);
    }

    // output layer (H -> 64, identity)
    gemm_bf_kernel<64><<<GEMM_GRID, GEMM_BLK, 0, stream>>>(
        xc_x, wT + (size_t)7 * 32768, normb, y);
    gather_fin64<<<NNODES / 16, 256, 0, stream>>>(
        y, row_ptr, sorted_src, normb, b_out, xout, perm);
}

// Round 3
// 958.136 us; speedup vs baseline: 1.2601x; 1.2601x over previous
//
#include <hip/hip_runtime.h>

#define NNODES 50000
#define NPAD   50048   // 391 * 128
#define NEDGES 800000
#define HDIM 128
#define OUTDIM 64

#define GEMM_GRID 196
#define GEMM_BLK  512
#define GEMM_WAVES (GEMM_GRID * (GEMM_BLK / 64))  // 1568
#define GEMM_TILES (NPAD / 16)                    // 3128

#define DBUCKETS 512

typedef short short8 __attribute__((ext_vector_type(8)));
typedef _Float16 half8 __attribute__((ext_vector_type(8)));
typedef _Float16 half4 __attribute__((ext_vector_type(4)));
typedef float f32x4 __attribute__((ext_vector_type(4)));
typedef float f32x8 __attribute__((ext_vector_type(8)));

__device__ __forceinline__ unsigned short f2bf(float f) {
    unsigned int u = __builtin_bit_cast(unsigned int, f);
    unsigned int r = (u + 0x7FFFu + ((u >> 16) & 1u)) >> 16;
    return (unsigned short)r;
}
__device__ __forceinline__ float bf2f(unsigned short b) {
    unsigned int u = ((unsigned int)b) << 16;
    return __builtin_bit_cast(float, u);
}

// ---------------- CSR build ----------------
__global__ void count_kernel(const int* __restrict__ dst, int* __restrict__ deg,
                             int* __restrict__ epos) {
    int e = blockIdx.x * 256 + threadIdx.x;
    if (e < NEDGES) epos[e] = atomicAdd(&deg[dst[e]], 1);
}

__global__ __launch_bounds__(256) void bsum_kernel(const int* __restrict__ deg,
                                                   int* __restrict__ bsum) {
    __shared__ int red[256];
    int i = blockIdx.x * 256 + threadIdx.x;
    red[threadIdx.x] = (i < NNODES) ? deg[i] : 0;
    __syncthreads();
    for (int off = 128; off; off >>= 1) {
        if (threadIdx.x < off) red[threadIdx.x] += red[threadIdx.x + off];
        __syncthreads();
    }
    if (threadIdx.x == 0) bsum[blockIdx.x] = red[0];
}

__global__ __launch_bounds__(256) void bscan_kernel(const int* __restrict__ bsum,
                                                    int* __restrict__ bofs) {
    __shared__ int s[256];
    int t = threadIdx.x;
    int v = (t < 196) ? bsum[t] : 0;
    s[t] = v;
    __syncthreads();
    for (int off = 1; off < 256; off <<= 1) {
        int u = (t >= off) ? s[t - off] : 0;
        __syncthreads();
        s[t] += u;
        __syncthreads();
    }
    if (t < 196) bofs[t] = s[t] - v;  // exclusive
}

__global__ __launch_bounds__(256) void emit_kernel(
    const int* __restrict__ deg, const int* __restrict__ bofs,
    int* __restrict__ row_ptr, float* __restrict__ norm) {
    __shared__ int s[256];
    int t = threadIdx.x;
    int i = blockIdx.x * 256 + t;
    int v = (i < NNODES) ? deg[i] : 0;
    s[t] = v;
    __syncthreads();
    for (int off = 1; off < 256; off <<= 1) {
        int u = (t >= off) ? s[t - off] : 0;
        __syncthreads();
        s[t] += u;
        __syncthreads();
    }
    int excl = s[t] - v + bofs[blockIdx.x];
    if (i < NNODES) {
        row_ptr[i] = excl;
        norm[i] = rsqrtf(1.0f + (float)v);
    }
    if (i == NNODES - 1) row_ptr[NNODES] = NEDGES;
}

__global__ void fill_kernel(const int* __restrict__ src, const int* __restrict__ dst,
                            const int* __restrict__ epos, const int* __restrict__ row_ptr,
                            int* __restrict__ sorted_src) {
    int e = blockIdx.x * 256 + threadIdx.x;
    if (e < NEDGES) sorted_src[row_ptr[dst[e]] + epos[e]] = src[e];
}

// ------- degree-sorted node permutation (contention-free counting sort) -----
// LDS histogram per block, then <=~40 global atomics per block.
__global__ __launch_bounds__(256) void dhist2_kernel(const int* __restrict__ deg,
                                                     int* __restrict__ dcount) {
    __shared__ int h[DBUCKETS];
    for (int b = threadIdx.x; b < DBUCKETS; b += 256) h[b] = 0;
    __syncthreads();
    int i = blockIdx.x * 256 + threadIdx.x;
    if (i < NNODES) atomicAdd(&h[min(deg[i], DBUCKETS - 1)], 1);
    __syncthreads();
    for (int b = threadIdx.x; b < DBUCKETS; b += 256)
        if (h[b]) atomicAdd(&dcount[b], h[b]);
}

__global__ __launch_bounds__(DBUCKETS) void dscan_kernel(const int* __restrict__ dcount,
                                                         int* __restrict__ dofs) {
    __shared__ int s[DBUCKETS];
    int t = threadIdx.x;
    int v = dcount[t];
    s[t] = v;
    __syncthreads();
    for (int off = 1; off < DBUCKETS; off <<= 1) {
        int u = (t >= off) ? s[t - off] : 0;
        __syncthreads();
        s[t] += u;
        __syncthreads();
    }
    dofs[t] = s[t] - v;  // exclusive
}

// Two-phase scatter: LDS rank within (block,bucket); one global atomic per
// (block,bucket) reserves a contiguous span. Order within bucket arbitrary.
__global__ __launch_bounds__(256) void dscatter2_kernel(
    const int* __restrict__ deg, int* __restrict__ dfill,
    const int* __restrict__ dofs, int* __restrict__ perm) {
    __shared__ int h[DBUCKETS];
    __shared__ int base[DBUCKETS];
    for (int b = threadIdx.x; b < DBUCKETS; b += 256) h[b] = 0;
    __syncthreads();
    int i = blockIdx.x * 256 + threadIdx.x;
    int b = -1, lrank = 0;
    if (i < NNODES) {
        b = min(deg[i], DBUCKETS - 1);
        lrank = atomicAdd(&h[b], 1);
    }
    __syncthreads();
    for (int bb = threadIdx.x; bb < DBUCKETS; bb += 256) {
        int c = h[bb];
        base[bb] = c ? atomicAdd(&dfill[bb], c) : 0;
    }
    __syncthreads();
    if (b >= 0) perm[dofs[b] + base[b] + lrank] = i;
}

// ---------------- weight prep ----------------
// bf16 hi/lo (wT): w_in slot 0, w1[m] slot 1+m, w_out slot 7 (64 rows).
// f16 single (w2f): w2[m] at m*16384, layout [n][128].
__global__ __launch_bounds__(256) void prep_w_kernel(
    const float* __restrict__ w_in, const float* __restrict__ w1,
    const float* __restrict__ w2, const float* __restrict__ w_out,
    unsigned short* __restrict__ wT, _Float16* __restrict__ w2f) {
    int idx = blockIdx.x * 256 + threadIdx.x;  // total 221184 = 864*256
    if (idx < 16384 + 98304) {
        const float* W;
        unsigned short* o;
        int e;
        if (idx < 16384) {
            W = w_in; o = wT; e = idx;
        } else {
            int j = idx - 16384; int m = j >> 14; e = j & 16383;
            W = w1 + ((size_t)m << 14); o = wT + (size_t)(1 + m) * 32768;
        }
        int k = e >> 7, n = e & 127;
        float v = W[e];
        unsigned short h = f2bf(v);
        o[(size_t)n * 256 + k] = h;
        o[(size_t)n * 256 + 128 + k] = f2bf(v - bf2f(h));
    } else if (idx < 16384 + 196608) {
        int j = idx - 16384 - 98304; int m = j >> 14; int e = j & 16383;
        int k = e >> 7, n = e & 127;
        w2f[(size_t)m * 16384 + n * 128 + k] = (_Float16)w2[((size_t)m << 14) + e];
    } else {
        int e = idx - 212992;  // w_out: 8192 elements
        int k = e >> 6, n = e & 63;
        float v = w_out[e];
        unsigned short h = f2bf(v);
        unsigned short* o = wT + (size_t)7 * 32768;
        o[(size_t)n * 256 + k] = h;
        o[(size_t)n * 256 + 128 + k] = f2bf(v - bf2f(h));
    }
}

// ---------------- x split (input layer only) ----------------
__global__ __launch_bounds__(256) void split_x_kernel(
    const float* __restrict__ x, unsigned short* __restrict__ xc) {
    int gid = blockIdx.x * 256 + threadIdx.x;
    int row = gid >> 6;
    int kk = (gid & 63) * 2;
    float2 v = {0.f, 0.f};
    if (row < NNODES) v = *(const float2*)(x + (size_t)row * 128 + kk);
    unsigned short h0 = f2bf(v.x), h1 = f2bf(v.y);
    unsigned short l0 = f2bf(v.x - bf2f(h0)), l1 = f2bf(v.y - bf2f(h1));
    *(unsigned int*)(xc + (size_t)row * 256 + kk) =
        (unsigned int)h0 | ((unsigned int)h1 << 16);
    *(unsigned int*)(xc + (size_t)row * 256 + 128 + kk) =
        (unsigned int)l0 | ((unsigned int)l1 << 16);
}

// ---------------- bf16 hi/lo streaming MFMA GEMM ----------------
// Whole B (hi+lo, [NCOLS][256] ushort) staged once into LDS with chunk-level
// XOR swizzle (16B chunk c of row n stored at c^(n&7)); single barrier; each
// wave then streams 2 independent 16-row tiles: A direct global->VGPR.
template <int NCOLS>
__global__ __launch_bounds__(GEMM_BLK) void gemm_bf_kernel(
    const unsigned short* __restrict__ xc, const unsigned short* __restrict__ wT,
    const float* __restrict__ norm, _Float16* __restrict__ y) {
    __shared__ unsigned short Blds[NCOLS * 256];
    const int t = threadIdx.x;
    const int wave = t >> 6, lane = t & 63, quad = lane >> 4, l16 = lane & 15;

    constexpr int NCH = NCOLS * 32;  // 16B chunks total
#pragma unroll
    for (int i = 0; i < NCH / GEMM_BLK; ++i) {
        int C = i * GEMM_BLK + t;
        int n = C >> 5, c = C & 31;
        const unsigned short* gp = wT + ((size_t)n << 8) + ((c ^ (n & 7)) << 3);
        unsigned short* lp = Blds + ((size_t)C << 3);
        __builtin_amdgcn_global_load_lds(
            (const __attribute__((address_space(1))) void*)gp,
            (__attribute__((address_space(3))) void*)lp, 16, 0, 0);
    }
    __syncthreads();

    const int wid = blockIdx.x * (GEMM_BLK / 64) + wave;
    const int sw = l16 & 7;
    const bool has1 = (wid + GEMM_WAVES) < GEMM_TILES;
    const int rb0 = wid * 16;
    const int rb1 = has1 ? (wid + GEMM_WAVES) * 16 : 0;

    short8 a0[8], a1[8];
    const unsigned short* ap0 = xc + ((size_t)(rb0 + l16) << 8) + quad * 8;
    const unsigned short* ap1 = xc + ((size_t)(rb1 + l16) << 8) + quad * 8;
#pragma unroll
    for (int ck = 0; ck < 8; ++ck) a0[ck] = *(const short8*)(ap0 + ck * 32);
#pragma unroll
    for (int ck = 0; ck < 8; ++ck) a1[ck] = *(const short8*)(ap1 + ck * 32);

    float nm0[4], nm1[4];
#pragma unroll
    for (int r = 0; r < 4; ++r) {
        int r0 = rb0 + quad * 4 + r;
        int r1 = rb1 + quad * 4 + r;
        nm0[r] = norm[r0 < NNODES ? r0 : 0];
        nm1[r] = norm[r1 < NNODES ? r1 : 0];
    }

#pragma unroll
    for (int nt = 0; nt < NCOLS / 16; ++nt) {
        const unsigned short* bp = Blds + ((size_t)(nt * 16 + l16) << 8);
        short8 bh[4], bl[4];
#pragma unroll
        for (int ck = 0; ck < 4; ++ck) {
            bh[ck] = *(const short8*)(bp + (((ck * 4 + quad) ^ sw) << 3));
            bl[ck] = *(const short8*)(bp + (((16 + ck * 4 + quad) ^ sw) << 3));
        }
        f32x4 ac0 = (f32x4){0.f, 0.f, 0.f, 0.f};
        f32x4 ac1 = (f32x4){0.f, 0.f, 0.f, 0.f};
#pragma unroll
        for (int ck = 0; ck < 4; ++ck) {
            ac0 = __builtin_amdgcn_mfma_f32_16x16x32_bf16(a0[ck], bh[ck], ac0, 0, 0, 0);
            ac1 = __builtin_amdgcn_mfma_f32_16x16x32_bf16(a1[ck], bh[ck], ac1, 0, 0, 0);
            ac0 = __builtin_amdgcn_mfma_f32_16x16x32_bf16(a0[ck], bl[ck], ac0, 0, 0, 0);
            ac1 = __builtin_amdgcn_mfma_f32_16x16x32_bf16(a1[ck], bl[ck], ac1, 0, 0, 0);
            ac0 = __builtin_amdgcn_mfma_f32_16x16x32_bf16(a0[4 + ck], bh[ck], ac0, 0, 0, 0);
            ac1 = __builtin_amdgcn_mfma_f32_16x16x32_bf16(a1[4 + ck], bh[ck], ac1, 0, 0, 0);
        }
        int col = nt * 16 + l16;
#pragma unroll
        for (int r = 0; r < 4; ++r) {
            int r0 = rb0 + quad * 4 + r;
            if (r0 < NNODES) y[(size_t)r0 * NCOLS + col] = (_Float16)(ac0[r] * nm0[r]);
            int r1 = rb1 + quad * 4 + r;
            if (has1 && r1 < NNODES) y[(size_t)r1 * NCOLS + col] = (_Float16)(ac1[r] * nm1[r]);
        }
    }
}

// ---------------- f16 streaming MFMA GEMM (x-conv) ----------------
__global__ __launch_bounds__(GEMM_BLK) void gemm_f16_kernel(
    const _Float16* __restrict__ A, const _Float16* __restrict__ wf,
    const float* __restrict__ norm, _Float16* __restrict__ y) {
    __shared__ _Float16 Blds[128 * 128];
    const int t = threadIdx.x;
    const int wave = t >> 6, lane = t & 63, quad = lane >> 4, l16 = lane & 15;

#pragma unroll
    for (int i = 0; i < 2048 / GEMM_BLK; ++i) {  // 128 rows x 16 chunks
        int C = i * GEMM_BLK + t;
        int n = C >> 4, c = C & 15;
        const _Float16* gp = wf + ((size_t)n << 7) + ((c ^ (n & 7)) << 3);
        _Float16* lp = Blds + ((size_t)C << 3);
        __builtin_amdgcn_global_load_lds(
            (const __attribute__((address_space(1))) void*)gp,
            (__attribute__((address_space(3))) void*)lp, 16, 0, 0);
    }
    __syncthreads();

    const int wid = blockIdx.x * (GEMM_BLK / 64) + wave;
    const int sw = l16 & 7;
    const bool has1 = (wid + GEMM_WAVES) < GEMM_TILES;
    const int rb0 = wid * 16;
    const int rb1 = has1 ? (wid + GEMM_WAVES) * 16 : 0;

    half8 a0[4], a1[4];
    const _Float16* ap0 = A + ((size_t)(rb0 + l16) << 7) + quad * 8;
    const _Float16* ap1 = A + ((size_t)(rb1 + l16) << 7) + quad * 8;
#pragma unroll
    for (int ck = 0; ck < 4; ++ck) a0[ck] = *(const half8*)(ap0 + ck * 32);
#pragma unroll
    for (int ck = 0; ck < 4; ++ck) a1[ck] = *(const half8*)(ap1 + ck * 32);

    float nm0[4], nm1[4];
#pragma unroll
    for (int r = 0; r < 4; ++r) {
        int r0 = rb0 + quad * 4 + r;
        int r1 = rb1 + quad * 4 + r;
        nm0[r] = norm[r0 < NNODES ? r0 : 0];
        nm1[r] = norm[r1 < NNODES ? r1 : 0];
    }

#pragma unroll
    for (int nt = 0; nt < 8; ++nt) {
        const _Float16* bp = Blds + ((size_t)(nt * 16 + l16) << 7);
        half8 b[4];
#pragma unroll
        for (int ck = 0; ck < 4; ++ck)
            b[ck] = *(const half8*)(bp + (((ck * 4 + quad) ^ sw) << 3));
        f32x4 ac0 = (f32x4){0.f, 0.f, 0.f, 0.f};
        f32x4 ac1 = (f32x4){0.f, 0.f, 0.f, 0.f};
#pragma unroll
        for (int ck = 0; ck < 4; ++ck) {
            ac0 = __builtin_amdgcn_mfma_f32_16x16x32_f16(a0[ck], b[ck], ac0, 0, 0, 0);
            ac1 = __builtin_amdgcn_mfma_f32_16x16x32_f16(a1[ck], b[ck], ac1, 0, 0, 0);
        }
        int col = nt * 16 + l16;
#pragma unroll
        for (int r = 0; r < 4; ++r) {
            int r0 = rb0 + quad * 4 + r;
            if (r0 < NNODES) y[(size_t)r0 * 128 + col] = (_Float16)(ac0[r] * nm0[r]);
            int r1 = rb1 + quad * 4 + r;
            if (has1 && r1 < NNODES) y[(size_t)r1 * 128 + col] = (_Float16)(ac1[r] * nm1[r]);
        }
    }
}

// ---------------- fused gather + finalize (F=128, fp16 y) ----------------
// Nodes processed in degree-sorted order (perm) so the 4 nodes sharing a
// wave have near-equal degree (dmax ~= deg, minimal wasted slots).
// 16 lanes per node, 16B per lane; 8-deep unroll = 32 rows in flight/wave.
template <int MODE, bool WOUT, bool OUT16>
__global__ __launch_bounds__(256) void gather_fin128(
    const _Float16* __restrict__ y, const int* __restrict__ row_ptr,
    const int* __restrict__ sorted_src, const float* __restrict__ norm,
    const float* __restrict__ bias, const unsigned short* __restrict__ xcres,
    float* __restrict__ out, unsigned short* __restrict__ xcout,
    _Float16* __restrict__ h16, const int* __restrict__ perm) {
    const int wave = threadIdx.x >> 6;
    const int lane = threadIdx.x & 63;
    const int g = lane >> 4, j = lane & 15;
    const int n = perm[blockIdx.x * 16 + wave * 4 + g];
    const int beg = row_ptr[n];
    const int deg = row_ptr[n + 1] - beg;
    int dmax = deg;
    dmax = max(dmax, __shfl_xor(dmax, 16));
    dmax = max(dmax, __shfl_xor(dmax, 32));

    f32x8 acc = (f32x8){0.f, 0.f, 0.f, 0.f, 0.f, 0.f, 0.f, 0.f};

    for (int i = 0; i < dmax; i += 8) {
        int sarr[8];
#pragma unroll
        for (int u = 0; u < 8; ++u)
            sarr[u] = (i + u < deg) ? sorted_src[beg + i + u] : -1;
        half8 h[8];
#pragma unroll
        for (int u = 0; u < 8; ++u)
            if (sarr[u] >= 0)
                h[u] = *(const half8*)(y + ((size_t)sarr[u] << 7) + j * 8);
#pragma unroll
        for (int u = 0; u < 8; ++u)
            if (sarr[u] >= 0) acc += __builtin_convertvector(h[u], f32x8);
    }

    const half8 sh = *(const half8*)(y + ((size_t)n << 7) + j * 8);
    const float4 b0 = *(const float4*)(bias + j * 8);
    const float4 b1 = *(const float4*)(bias + j * 8 + 4);
    const float bb[8] = {b0.x, b0.y, b0.z, b0.w, b1.x, b1.y, b1.z, b1.w};
    const float nm = norm[n];
    float v[8];
#pragma unroll
    for (int c = 0; c < 8; ++c) {
        float t = (acc[c] + (float)sh[c]) * nm + bb[c];
        v[c] = t >= 0.f ? t : 0.01f * t;
    }
    if (MODE == 1) {
        short8 hw = *(const short8*)(xcres + ((size_t)n << 8) + j * 8);
        short8 lw = *(const short8*)(xcres + ((size_t)n << 8) + 128 + j * 8);
#pragma unroll
        for (int c = 0; c < 8; ++c) {
            float xr = bf2f((unsigned short)hw[c]) + bf2f((unsigned short)lw[c]);
            v[c] = (xr + v[c]) * 0.5f;
        }
    }
    if (WOUT) {
        float4 o0 = {v[0], v[1], v[2], v[3]};
        float4 o1 = {v[4], v[5], v[6], v[7]};
        *(float4*)(out + ((size_t)n << 7) + j * 8) = o0;
        *(float4*)(out + ((size_t)n << 7) + j * 8 + 4) = o1;
    }
    if (OUT16) {
        half8 o;
#pragma unroll
        for (int c = 0; c < 8; ++c) o[c] = (_Float16)v[c];
        *(half8*)(h16 + ((size_t)n << 7) + j * 8) = o;
    } else {
        short8 hi, lo;
#pragma unroll
        for (int c = 0; c < 8; ++c) {
            unsigned short hv = f2bf(v[c]);
            hi[c] = (short)hv;
            lo[c] = (short)f2bf(v[c] - bf2f(hv));
        }
        *(short8*)(xcout + ((size_t)n << 8) + j * 8) = hi;
        *(short8*)(xcout + ((size_t)n << 8) + 128 + j * 8) = lo;
    }
}

// ---------------- final gather (F=64, identity, fp16 y) ----------------
__global__ __launch_bounds__(256) void gather_fin64(
    const _Float16* __restrict__ y, const int* __restrict__ row_ptr,
    const int* __restrict__ sorted_src, const float* __restrict__ norm,
    const float* __restrict__ bias, float* __restrict__ out,
    const int* __restrict__ perm) {
    const int wave = threadIdx.x >> 6;
    const int lane = threadIdx.x & 63;
    const int g = lane >> 4, j = lane & 15;
    const int n = perm[blockIdx.x * 16 + wave * 4 + g];
    const int beg = row_ptr[n];
    const int deg = row_ptr[n + 1] - beg;
    int dmax = deg;
    dmax = max(dmax, __shfl_xor(dmax, 16));
    dmax = max(dmax, __shfl_xor(dmax, 32));

    f32x4 acc = (f32x4){0.f, 0.f, 0.f, 0.f};
    for (int i = 0; i < dmax; i += 8) {
        int sarr[8];
#pragma unroll
        for (int u = 0; u < 8; ++u)
            sarr[u] = (i + u < deg) ? sorted_src[beg + i + u] : -1;
        half4 h[8];
#pragma unroll
        for (int u = 0; u < 8; ++u)
            if (sarr[u] >= 0)
                h[u] = *(const half4*)(y + ((size_t)sarr[u] << 6) + j * 4);
#pragma unroll
        for (int u = 0; u < 8; ++u)
            if (sarr[u] >= 0) acc += __builtin_convertvector(h[u], f32x4);
    }

    const half4 sh = *(const half4*)(y + ((size_t)n << 6) + j * 4);
    const float4 b = *(const float4*)(bias + j * 4);
    const float bb[4] = {b.x, b.y, b.z, b.w};
    const float nm = norm[n];
    float4 o;
    o.x = (acc[0] + (float)sh[0]) * nm + bb[0];
    o.y = (acc[1] + (float)sh[1]) * nm + bb[1];
    o.z = (acc[2] + (float)sh[2]) * nm + bb[2];
    o.w = (acc[3] + (float)sh[3]) * nm + bb[3];
    *(float4*)(out + ((size_t)n << 6) + j * 4) = o;
}

extern "C" void kernel_launch(void* const* d_in, const int* in_sizes, int n_in,
                              void* d_out, int out_size, void* d_ws, size_t ws_size,
                              hipStream_t stream) {
    const float* inputs = (const float*)d_in[0];
    const int* edges = (const int*)d_in[1];
    const int* src = edges;
    const int* dst = edges + NEDGES;
    const float* w_in  = (const float*)d_in[2];
    const float* b_in  = (const float*)d_in[3];
    const float* w1    = (const float*)d_in[4];
    const float* b1    = (const float*)d_in[5];
    const float* w2    = (const float*)d_in[6];
    const float* b2    = (const float*)d_in[7];
    const float* w_out = (const float*)d_in[8];
    const float* b_out = (const float*)d_in[9];

    float* out  = (float*)d_out;
    float* xout = out;                                // [N, 64]
    float* x    = out + (size_t)NNODES * OUTDIM;      // [N, 128] fp32 x (final only)

    char* p = (char*)d_ws;
    auto alloc = [&](size_t bytes) {
        char* r = p;
        p += (bytes + 63) & ~(size_t)63;
        return r;
    };
    int* deg        = (int*)alloc(NNODES * 4);
    int* epos       = (int*)alloc(NEDGES * 4);
    int* row_ptr    = (int*)alloc((NNODES + 1) * 4);
    int* bsum       = (int*)alloc(256 * 4);
    int* bofs       = (int*)alloc(256 * 4);
    int* sorted_src = (int*)alloc(NEDGES * 4);
    float* normb    = (float*)alloc(NNODES * 4);
    int* dctr       = (int*)alloc(2 * DBUCKETS * 4);   // dcount | dfill
    int* dofs       = (int*)alloc(DBUCKETS * 4);
    int* perm       = (int*)alloc(NNODES * 4);
    unsigned short* wT = (unsigned short*)alloc((size_t)245760 * 2);  // 7*32768+16384
    _Float16* w2f   = (_Float16*)alloc((size_t)6 * 16384 * 2);
    unsigned short* xc_x = (unsigned short*)alloc((size_t)NPAD * 256 * 2);
    unsigned short* xc_in = (unsigned short*)alloc((size_t)NPAD * 256 * 2);
    _Float16* h16   = (_Float16*)alloc((size_t)NPAD * 128 * 2);
    _Float16* y     = (_Float16*)alloc((size_t)NNODES * HDIM * 2);

    int* dcount = dctr;
    int* dfill  = dctr + DBUCKETS;

    // ---- CSR + norm + degree-sorted perm + weight prep ----
    hipMemsetAsync(deg, 0, NNODES * sizeof(int), stream);
    hipMemsetAsync(dctr, 0, 2 * DBUCKETS * sizeof(int), stream);
    count_kernel<<<(NEDGES + 255) / 256, 256, 0, stream>>>(dst, deg, epos);
    dhist2_kernel<<<196, 256, 0, stream>>>(deg, dcount);
    dscan_kernel<<<1, DBUCKETS, 0, stream>>>(dcount, dofs);
    dscatter2_kernel<<<196, 256, 0, stream>>>(deg, dfill, dofs, perm);
    bsum_kernel<<<196, 256, 0, stream>>>(deg, bsum);
    bscan_kernel<<<1, 256, 0, stream>>>(bsum, bofs);
    emit_kernel<<<196, 256, 0, stream>>>(deg, bofs, row_ptr, normb);
    fill_kernel<<<(NEDGES + 255) / 256, 256, 0, stream>>>(src, dst, epos, row_ptr, sorted_src);
    prep_w_kernel<<<864, 256, 0, stream>>>(w_in, w1, w2, w_out, wT, w2f);

    // input layer
    split_x_kernel<<<(NPAD * 64) / 256, 256, 0, stream>>>(inputs, xc_in);
    gemm_bf_kernel<128><<<GEMM_GRID, GEMM_BLK, 0, stream>>>(xc_in, wT, normb, y);
    gather_fin128<0, false, false><<<NNODES / 16, 256, 0, stream>>>(
        y, row_ptr, sorted_src, normb, b_in, nullptr, nullptr, xc_x, nullptr, perm);

    // 6 residual blocks
    for (int i = 0; i < 6; ++i) {
        gemm_bf_kernel<128><<<GEMM_GRID, GEMM_BLK, 0, stream>>>(
            xc_x, wT + (size_t)(1 + i) * 32768, normb, y);
        gather_fin128<0, false, true><<<NNODES / 16, 256, 0, stream>>>(
            y, row_ptr, sorted_src, normb, b1 + i * HDIM, nullptr, nullptr, nullptr, h16, perm);
        gemm_f16_kernel<<<GEMM_GRID, GEMM_BLK, 0, stream>>>(
            h16, w2f + (size_t)i * 16384, normb, y);
        if (i < 5)
            gather_fin128<1, false, false><<<NNODES / 16, 256, 0, stream>>>(
                y, row_ptr, sorted_src, normb, b2 + i * HDIM, xc_x, nullptr, xc_x, nullptr, perm);
        else
            gather_fin128<1, true, false><<<NNODES / 16, 256, 0, stream>>>(
                y, row_ptr, sorted_src, normb, b2 + i * HDIM, xc_x, x, xc_x, nullptr, perm);
    }

    // output layer (H -> 64, identity)
    gemm_bf_kernel<64><<<GEMM_GRID, GEMM_BLK, 0, stream>>>(
        xc_x, wT + (size_t)7 * 32768, normb, y);
    gather_fin64<<<NNODES / 16, 256, 0, stream>>>(
        y, row_ptr, sorted_src, normb, b_out, xout, perm);
}

// Round 5
// 784.400 us; speedup vs baseline: 1.5391x; 1.2215x over previous
//
#include <hip/hip_runtime.h>

#define NNODES 50000
#define NPAD   50048   // 391 * 128
#define NEDGES 800000
#define HDIM 128
#define OUTDIM 64

#define GEMM_GRID 391
#define GEMM_BLK  512
#define GEMM_TILES (NPAD / 16)  // 3128 = 391 * 8 : exactly 1 tile per wave

typedef short short8 __attribute__((ext_vector_type(8)));
typedef _Float16 half8 __attribute__((ext_vector_type(8)));
typedef _Float16 half4 __attribute__((ext_vector_type(4)));
typedef float f32x4 __attribute__((ext_vector_type(4)));
typedef float f32x8 __attribute__((ext_vector_type(8)));

__device__ __forceinline__ unsigned short f2bf(float f) {
    unsigned int u = __builtin_bit_cast(unsigned int, f);
    unsigned int r = (u + 0x7FFFu + ((u >> 16) & 1u)) >> 16;
    return (unsigned short)r;
}
__device__ __forceinline__ float bf2f(unsigned short b) {
    unsigned int u = ((unsigned int)b) << 16;
    return __builtin_bit_cast(float, u);
}

// ---------------- CSR build ----------------
__global__ void count_kernel(const int* __restrict__ dst, int* __restrict__ deg,
                             int* __restrict__ epos) {
    int e = blockIdx.x * 256 + threadIdx.x;
    if (e < NEDGES) epos[e] = atomicAdd(&deg[dst[e]], 1);
}

__global__ __launch_bounds__(256) void bsum_kernel(const int* __restrict__ deg,
                                                   int* __restrict__ bsum) {
    __shared__ int red[256];
    int i = blockIdx.x * 256 + threadIdx.x;
    red[threadIdx.x] = (i < NNODES) ? deg[i] : 0;
    __syncthreads();
    for (int off = 128; off; off >>= 1) {
        if (threadIdx.x < off) red[threadIdx.x] += red[threadIdx.x + off];
        __syncthreads();
    }
    if (threadIdx.x == 0) bsum[blockIdx.x] = red[0];
}

__global__ __launch_bounds__(256) void bscan_kernel(const int* __restrict__ bsum,
                                                    int* __restrict__ bofs) {
    __shared__ int s[256];
    int t = threadIdx.x;
    int v = (t < 196) ? bsum[t] : 0;
    s[t] = v;
    __syncthreads();
    for (int off = 1; off < 256; off <<= 1) {
        int u = (t >= off) ? s[t - off] : 0;
        __syncthreads();
        s[t] += u;
        __syncthreads();
    }
    if (t < 196) bofs[t] = s[t] - v;  // exclusive
}

__global__ __launch_bounds__(256) void emit_kernel(
    const int* __restrict__ deg, const int* __restrict__ bofs,
    int* __restrict__ row_ptr, float* __restrict__ norm) {
    __shared__ int s[256];
    int t = threadIdx.x;
    int i = blockIdx.x * 256 + t;
    int v = (i < NNODES) ? deg[i] : 0;
    s[t] = v;
    __syncthreads();
    for (int off = 1; off < 256; off <<= 1) {
        int u = (t >= off) ? s[t - off] : 0;
        __syncthreads();
        s[t] += u;
        __syncthreads();
    }
    int excl = s[t] - v + bofs[blockIdx.x];
    if (i < NNODES) {
        row_ptr[i] = excl;
        norm[i] = rsqrtf(1.0f + (float)v);
    }
    if (i == NNODES - 1) row_ptr[NNODES] = NEDGES;
}

__global__ void fill_kernel(const int* __restrict__ src, const int* __restrict__ dst,
                            const int* __restrict__ epos, const int* __restrict__ row_ptr,
                            int* __restrict__ sorted_src) {
    int e = blockIdx.x * 256 + threadIdx.x;
    if (e < NEDGES) sorted_src[row_ptr[dst[e]] + epos[e]] = src[e];
}

// ---------------- weight prep ----------------
// bf16 hi/lo (wT): w_in slot 0, w1[m] slot 1+m, w_out slot 7 (64 rows).
// f16 single (w2f): w2[m] at m*16384, layout [n][128].
__global__ __launch_bounds__(256) void prep_w_kernel(
    const float* __restrict__ w_in, const float* __restrict__ w1,
    const float* __restrict__ w2, const float* __restrict__ w_out,
    unsigned short* __restrict__ wT, _Float16* __restrict__ w2f) {
    int idx = blockIdx.x * 256 + threadIdx.x;  // total 221184 = 864*256
    if (idx < 16384 + 98304) {
        const float* W;
        unsigned short* o;
        int e;
        if (idx < 16384) {
            W = w_in; o = wT; e = idx;
        } else {
            int j = idx - 16384; int m = j >> 14; e = j & 16383;
            W = w1 + ((size_t)m << 14); o = wT + (size_t)(1 + m) * 32768;
        }
        int k = e >> 7, n = e & 127;
        float v = W[e];
        unsigned short h = f2bf(v);
        o[(size_t)n * 256 + k] = h;
        o[(size_t)n * 256 + 128 + k] = f2bf(v - bf2f(h));
    } else if (idx < 16384 + 196608) {
        int j = idx - 16384 - 98304; int m = j >> 14; int e = j & 16383;
        int k = e >> 7, n = e & 127;
        w2f[(size_t)m * 16384 + n * 128 + k] = (_Float16)w2[((size_t)m << 14) + e];
    } else {
        int e = idx - 212992;  // w_out: 8192 elements
        int k = e >> 6, n = e & 63;
        float v = w_out[e];
        unsigned short h = f2bf(v);
        unsigned short* o = wT + (size_t)7 * 32768;
        o[(size_t)n * 256 + k] = h;
        o[(size_t)n * 256 + 128 + k] = f2bf(v - bf2f(h));
    }
}

// ---------------- x split (input layer only) ----------------
__global__ __launch_bounds__(256) void split_x_kernel(
    const float* __restrict__ x, unsigned short* __restrict__ xc) {
    int gid = blockIdx.x * 256 + threadIdx.x;
    int row = gid >> 6;
    int kk = (gid & 63) * 2;
    float2 v = {0.f, 0.f};
    if (row < NNODES) v = *(const float2*)(x + (size_t)row * 128 + kk);
    unsigned short h0 = f2bf(v.x), h1 = f2bf(v.y);
    unsigned short l0 = f2bf(v.x - bf2f(h0)), l1 = f2bf(v.y - bf2f(h1));
    *(unsigned int*)(xc + (size_t)row * 256 + kk) =
        (unsigned int)h0 | ((unsigned int)h1 << 16);
    *(unsigned int*)(xc + (size_t)row * 256 + 128 + kk) =
        (unsigned int)l0 | ((unsigned int)l1 << 16);
}

// ---------------- bf16 hi/lo streaming MFMA GEMM ----------------
// Whole B (hi+lo) staged once into LDS (chunk-level XOR swizzle); single
// barrier; 1 output tile (16 rows) per wave, grid*waves == tiles exactly.
// 391 blocks -> all 256 CUs active, 2 blocks/CU co-resident (64KB LDS)
// so block 2's stage overlaps block 1's compute.
template <int NCOLS>
__global__ __launch_bounds__(GEMM_BLK) void gemm_bf_kernel(
    const unsigned short* __restrict__ xc, const unsigned short* __restrict__ wT,
    const float* __restrict__ norm, _Float16* __restrict__ y) {
    __shared__ unsigned short Blds[NCOLS * 256];
    const int t = threadIdx.x;
    const int wave = t >> 6, lane = t & 63, quad = lane >> 4, l16 = lane & 15;

    constexpr int NCH = NCOLS * 32;  // 16B chunks total
#pragma unroll
    for (int i = 0; i < NCH / GEMM_BLK; ++i) {
        int C = i * GEMM_BLK + t;
        int n = C >> 5, c = C & 31;
        const unsigned short* gp = wT + ((size_t)n << 8) + ((c ^ (n & 7)) << 3);
        unsigned short* lp = Blds + ((size_t)C << 3);
        __builtin_amdgcn_global_load_lds(
            (const __attribute__((address_space(1))) void*)gp,
            (__attribute__((address_space(3))) void*)lp, 16, 0, 0);
    }
    __syncthreads();

    const int wid = blockIdx.x * (GEMM_BLK / 64) + wave;
    const int sw = l16 & 7;
    const int rb0 = wid * 16;

    short8 a0[8];
    const unsigned short* ap0 = xc + ((size_t)(rb0 + l16) << 8) + quad * 8;
#pragma unroll
    for (int ck = 0; ck < 8; ++ck) a0[ck] = *(const short8*)(ap0 + ck * 32);

    float nm0[4];
#pragma unroll
    for (int r = 0; r < 4; ++r) {
        int r0 = rb0 + quad * 4 + r;
        nm0[r] = norm[r0 < NNODES ? r0 : 0];
    }

#pragma unroll
    for (int nt = 0; nt < NCOLS / 16; ++nt) {
        const unsigned short* bp = Blds + ((size_t)(nt * 16 + l16) << 8);
        short8 bh[4], bl[4];
#pragma unroll
        for (int ck = 0; ck < 4; ++ck) {
            bh[ck] = *(const short8*)(bp + (((ck * 4 + quad) ^ sw) << 3));
            bl[ck] = *(const short8*)(bp + (((16 + ck * 4 + quad) ^ sw) << 3));
        }
        f32x4 ac0 = (f32x4){0.f, 0.f, 0.f, 0.f};
#pragma unroll
        for (int ck = 0; ck < 4; ++ck) {
            ac0 = __builtin_amdgcn_mfma_f32_16x16x32_bf16(a0[ck], bh[ck], ac0, 0, 0, 0);
            ac0 = __builtin_amdgcn_mfma_f32_16x16x32_bf16(a0[ck], bl[ck], ac0, 0, 0, 0);
            ac0 = __builtin_amdgcn_mfma_f32_16x16x32_bf16(a0[4 + ck], bh[ck], ac0, 0, 0, 0);
        }
        int col = nt * 16 + l16;
#pragma unroll
        for (int r = 0; r < 4; ++r) {
            int r0 = rb0 + quad * 4 + r;
            if (r0 < NNODES) y[(size_t)r0 * NCOLS + col] = (_Float16)(ac0[r] * nm0[r]);
        }
    }
}

// ---------------- f16 streaming MFMA GEMM (x-conv) ----------------
__global__ __launch_bounds__(GEMM_BLK) void gemm_f16_kernel(
    const _Float16* __restrict__ A, const _Float16* __restrict__ wf,
    const float* __restrict__ norm, _Float16* __restrict__ y) {
    __shared__ _Float16 Blds[128 * 128];
    const int t = threadIdx.x;
    const int wave = t >> 6, lane = t & 63, quad = lane >> 4, l16 = lane & 15;

#pragma unroll
    for (int i = 0; i < 2048 / GEMM_BLK; ++i) {  // 128 rows x 16 chunks
        int C = i * GEMM_BLK + t;
        int n = C >> 4, c = C & 15;
        const _Float16* gp = wf + ((size_t)n << 7) + ((c ^ (n & 7)) << 3);
        _Float16* lp = Blds + ((size_t)C << 3);
        __builtin_amdgcn_global_load_lds(
            (const __attribute__((address_space(1))) void*)gp,
            (__attribute__((address_space(3))) void*)lp, 16, 0, 0);
    }
    __syncthreads();

    const int wid = blockIdx.x * (GEMM_BLK / 64) + wave;
    const int sw = l16 & 7;
    const int rb0 = wid * 16;

    half8 a0[4];
    const _Float16* ap0 = A + ((size_t)(rb0 + l16) << 7) + quad * 8;
#pragma unroll
    for (int ck = 0; ck < 4; ++ck) a0[ck] = *(const half8*)(ap0 + ck * 32);

    float nm0[4];
#pragma unroll
    for (int r = 0; r < 4; ++r) {
        int r0 = rb0 + quad * 4 + r;
        nm0[r] = norm[r0 < NNODES ? r0 : 0];
    }

#pragma unroll
    for (int nt = 0; nt < 8; ++nt) {
        const _Float16* bp = Blds + ((size_t)(nt * 16 + l16) << 7);
        half8 b[4];
#pragma unroll
        for (int ck = 0; ck < 4; ++ck)
            b[ck] = *(const half8*)(bp + (((ck * 4 + quad) ^ sw) << 3));
        f32x4 ac0 = (f32x4){0.f, 0.f, 0.f, 0.f};
#pragma unroll
        for (int ck = 0; ck < 4; ++ck)
            ac0 = __builtin_amdgcn_mfma_f32_16x16x32_f16(a0[ck], b[ck], ac0, 0, 0, 0);
        int col = nt * 16 + l16;
#pragma unroll
        for (int r = 0; r < 4; ++r) {
            int r0 = rb0 + quad * 4 + r;
            if (r0 < NNODES) y[(size_t)r0 * 128 + col] = (_Float16)(ac0[r] * nm0[r]);
        }
    }
}

// ---------------- fused gather + finalize (F=128, fp16 y) ----------------
// Identity node order (locality!). 4 nodes per wave; 16 lanes per node,
// 16B per lane; 8-deep unroll = 32 rows in flight per wave.
// xcres loads / out stores are nontemporal: dead-after-use traffic must not
// evict the y rows (re-read ~16x) from L2/L3.
template <int MODE, bool WOUT, bool OUT16>
__global__ __launch_bounds__(256) void gather_fin128(
    const _Float16* __restrict__ y, const int* __restrict__ row_ptr,
    const int* __restrict__ sorted_src, const float* __restrict__ norm,
    const float* __restrict__ bias, const unsigned short* __restrict__ xcres,
    float* __restrict__ out, unsigned short* __restrict__ xcout,
    _Float16* __restrict__ h16) {
    const int wave = threadIdx.x >> 6;
    const int lane = threadIdx.x & 63;
    const int g = lane >> 4, j = lane & 15;
    const int n = blockIdx.x * 16 + wave * 4 + g;
    const int beg = row_ptr[n];
    const int deg = row_ptr[n + 1] - beg;
    int dmax = deg;
    dmax = max(dmax, __shfl_xor(dmax, 16));
    dmax = max(dmax, __shfl_xor(dmax, 32));

    f32x8 acc = (f32x8){0.f, 0.f, 0.f, 0.f, 0.f, 0.f, 0.f, 0.f};

    for (int i = 0; i < dmax; i += 8) {
        int sarr[8];
#pragma unroll
        for (int u = 0; u < 8; ++u)
            sarr[u] = (i + u < deg) ? sorted_src[beg + i + u] : -1;
        half8 h[8];
#pragma unroll
        for (int u = 0; u < 8; ++u)
            if (sarr[u] >= 0)
                h[u] = *(const half8*)(y + ((size_t)sarr[u] << 7) + j * 8);
#pragma unroll
        for (int u = 0; u < 8; ++u)
            if (sarr[u] >= 0) acc += __builtin_convertvector(h[u], f32x8);
    }

    const half8 sh = *(const half8*)(y + ((size_t)n << 7) + j * 8);
    const f32x4 b0 = *(const f32x4*)(bias + j * 8);
    const f32x4 b1 = *(const f32x4*)(bias + j * 8 + 4);
    const float bb[8] = {b0[0], b0[1], b0[2], b0[3], b1[0], b1[1], b1[2], b1[3]};
    const float nm = norm[n];
    float v[8];
#pragma unroll
    for (int c = 0; c < 8; ++c) {
        float t = (acc[c] + (float)sh[c]) * nm + bb[c];
        v[c] = t >= 0.f ? t : 0.01f * t;
    }
    if (MODE == 1) {
        short8 hw = __builtin_nontemporal_load(
            (const short8*)(xcres + ((size_t)n << 8) + j * 8));
        short8 lw = __builtin_nontemporal_load(
            (const short8*)(xcres + ((size_t)n << 8) + 128 + j * 8));
#pragma unroll
        for (int c = 0; c < 8; ++c) {
            float xr = bf2f((unsigned short)hw[c]) + bf2f((unsigned short)lw[c]);
            v[c] = (xr + v[c]) * 0.5f;
        }
    }
    if (WOUT) {
        f32x4 o0 = (f32x4){v[0], v[1], v[2], v[3]};
        f32x4 o1 = (f32x4){v[4], v[5], v[6], v[7]};
        __builtin_nontemporal_store(o0, (f32x4*)(out + ((size_t)n << 7) + j * 8));
        __builtin_nontemporal_store(o1, (f32x4*)(out + ((size_t)n << 7) + j * 8 + 4));
    }
    if (OUT16) {
        half8 o;
#pragma unroll
        for (int c = 0; c < 8; ++c) o[c] = (_Float16)v[c];
        *(half8*)(h16 + ((size_t)n << 7) + j * 8) = o;
    } else {
        short8 hi, lo;
#pragma unroll
        for (int c = 0; c < 8; ++c) {
            unsigned short hv = f2bf(v[c]);
            hi[c] = (short)hv;
            lo[c] = (short)f2bf(v[c] - bf2f(hv));
        }
        *(short8*)(xcout + ((size_t)n << 8) + j * 8) = hi;
        *(short8*)(xcout + ((size_t)n << 8) + 128 + j * 8) = lo;
    }
}

// ---------------- final gather (F=64, identity, fp16 y) ----------------
__global__ __launch_bounds__(256) void gather_fin64(
    const _Float16* __restrict__ y, const int* __restrict__ row_ptr,
    const int* __restrict__ sorted_src, const float* __restrict__ norm,
    const float* __restrict__ bias, float* __restrict__ out) {
    const int wave = threadIdx.x >> 6;
    const int lane = threadIdx.x & 63;
    const int g = lane >> 4, j = lane & 15;
    const int n = blockIdx.x * 16 + wave * 4 + g;
    const int beg = row_ptr[n];
    const int deg = row_ptr[n + 1] - beg;
    int dmax = deg;
    dmax = max(dmax, __shfl_xor(dmax, 16));
    dmax = max(dmax, __shfl_xor(dmax, 32));

    f32x4 acc = (f32x4){0.f, 0.f, 0.f, 0.f};
    for (int i = 0; i < dmax; i += 8) {
        int sarr[8];
#pragma unroll
        for (int u = 0; u < 8; ++u)
            sarr[u] = (i + u < deg) ? sorted_src[beg + i + u] : -1;
        half4 h[8];
#pragma unroll
        for (int u = 0; u < 8; ++u)
            if (sarr[u] >= 0)
                h[u] = *(const half4*)(y + ((size_t)sarr[u] << 6) + j * 4);
#pragma unroll
        for (int u = 0; u < 8; ++u)
            if (sarr[u] >= 0) acc += __builtin_convertvector(h[u], f32x4);
    }

    const half4 sh = *(const half4*)(y + ((size_t)n << 6) + j * 4);
    const f32x4 b = *(const f32x4*)(bias + j * 4);
    const float nm = norm[n];
    f32x4 o;
    o[0] = (acc[0] + (float)sh[0]) * nm + b[0];
    o[1] = (acc[1] + (float)sh[1]) * nm + b[1];
    o[2] = (acc[2] + (float)sh[2]) * nm + b[2];
    o[3] = (acc[3] + (float)sh[3]) * nm + b[3];
    __builtin_nontemporal_store(o, (f32x4*)(out + ((size_t)n << 6) + j * 4));
}

extern "C" void kernel_launch(void* const* d_in, const int* in_sizes, int n_in,
                              void* d_out, int out_size, void* d_ws, size_t ws_size,
                              hipStream_t stream) {
    const float* inputs = (const float*)d_in[0];
    const int* edges = (const int*)d_in[1];
    const int* src = edges;
    const int* dst = edges + NEDGES;
    const float* w_in  = (const float*)d_in[2];
    const float* b_in  = (const float*)d_in[3];
    const float* w1    = (const float*)d_in[4];
    const float* b1    = (const float*)d_in[5];
    const float* w2    = (const float*)d_in[6];
    const float* b2    = (const float*)d_in[7];
    const float* w_out = (const float*)d_in[8];
    const float* b_out = (const float*)d_in[9];

    float* out  = (float*)d_out;
    float* xout = out;                                // [N, 64]
    float* x    = out + (size_t)NNODES * OUTDIM;      // [N, 128] fp32 x (final only)

    char* p = (char*)d_ws;
    auto alloc = [&](size_t bytes) {
        char* r = p;
        p += (bytes + 63) & ~(size_t)63;
        return r;
    };
    int* deg        = (int*)alloc(NNODES * 4);
    int* epos       = (int*)alloc(NEDGES * 4);
    int* row_ptr    = (int*)alloc((NNODES + 1) * 4);
    int* bsum       = (int*)alloc(256 * 4);
    int* bofs       = (int*)alloc(256 * 4);
    int* sorted_src = (int*)alloc(NEDGES * 4);
    float* normb    = (float*)alloc(NNODES * 4);
    unsigned short* wT = (unsigned short*)alloc((size_t)245760 * 2);  // 7*32768+16384
    _Float16* w2f   = (_Float16*)alloc((size_t)6 * 16384 * 2);
    unsigned short* xc_x = (unsigned short*)alloc((size_t)NPAD * 256 * 2);
    unsigned short* xc_in = (unsigned short*)alloc((size_t)NPAD * 256 * 2);
    _Float16* h16   = (_Float16*)alloc((size_t)NPAD * 128 * 2);
    _Float16* y     = (_Float16*)alloc((size_t)NNODES * HDIM * 2);

    // ---- CSR + norm + weight prep ----
    hipMemsetAsync(deg, 0, NNODES * sizeof(int), stream);
    count_kernel<<<(NEDGES + 255) / 256, 256, 0, stream>>>(dst, deg, epos);
    bsum_kernel<<<196, 256, 0, stream>>>(deg, bsum);
    bscan_kernel<<<1, 256, 0, stream>>>(bsum, bofs);
    emit_kernel<<<196, 256, 0, stream>>>(deg, bofs, row_ptr, normb);
    fill_kernel<<<(NEDGES + 255) / 256, 256, 0, stream>>>(src, dst, epos, row_ptr, sorted_src);
    prep_w_kernel<<<864, 256, 0, stream>>>(w_in, w1, w2, w_out, wT, w2f);

    // input layer
    split_x_kernel<<<(NPAD * 64) / 256, 256, 0, stream>>>(inputs, xc_in);
    gemm_bf_kernel<128><<<GEMM_GRID, GEMM_BLK, 0, stream>>>(xc_in, wT, normb, y);
    gather_fin128<0, false, false><<<NNODES / 16, 256, 0, stream>>>(
        y, row_ptr, sorted_src, normb, b_in, nullptr, nullptr, xc_x, nullptr);

    // 6 residual blocks
    for (int i = 0; i < 6; ++i) {
        gemm_bf_kernel<128><<<GEMM_GRID, GEMM_BLK, 0, stream>>>(
            xc_x, wT + (size_t)(1 + i) * 32768, normb, y);
        gather_fin128<0, false, true><<<NNODES / 16, 256, 0, stream>>>(
            y, row_ptr, sorted_src, normb, b1 + i * HDIM, nullptr, nullptr, nullptr, h16);
        gemm_f16_kernel<<<GEMM_GRID, GEMM_BLK, 0, stream>>>(
            h16, w2f + (size_t)i * 16384, normb, y);
        if (i < 5)
            gather_fin128<1, false, false><<<NNODES / 16, 256, 0, stream>>>(
                y, row_ptr, sorted_src, normb, b2 + i * HDIM, xc_x, nullptr, xc_x, nullptr);
        else
            gather_fin128<1, true, false><<<NNODES / 16, 256, 0, stream>>>(
                y, row_ptr, sorted_src, normb, b2 + i * HDIM, xc_x, x, xc_x, nullptr);
    }

    // output layer (H -> 64, identity)
    gemm_bf_kernel<64><<<GEMM_GRID, GEMM_BLK, 0, stream>>>(
        xc_x, wT + (size_t)7 * 32768, normb, y);
    gather_fin64<<<NNODES / 16, 256, 0, stream>>>(
        y, row_ptr, sorted_src, normb, b_out, xout);
}

// Round 6
// 742.614 us; speedup vs baseline: 1.6258x; 1.0563x over previous
//
#include <hip/hip_runtime.h>

#define NNODES 50000
#define NPAD   50048   // 391 * 128
#define NEDGES 800000
#define HDIM 128
#define OUTDIM 64

#define GEMM_GRID 391
#define GEMM_BLK  512
#define GEMM_TILES (NPAD / 16)  // 3128 = 391 * 8 : exactly 1 tile per wave

typedef short short8 __attribute__((ext_vector_type(8)));
typedef _Float16 half8 __attribute__((ext_vector_type(8)));
typedef _Float16 half4 __attribute__((ext_vector_type(4)));
typedef float f32x4 __attribute__((ext_vector_type(4)));
typedef float f32x8 __attribute__((ext_vector_type(8)));

__device__ __forceinline__ unsigned short f2bf(float f) {
    unsigned int u = __builtin_bit_cast(unsigned int, f);
    unsigned int r = (u + 0x7FFFu + ((u >> 16) & 1u)) >> 16;
    return (unsigned short)r;
}
__device__ __forceinline__ float bf2f(unsigned short b) {
    unsigned int u = ((unsigned int)b) << 16;
    return __builtin_bit_cast(float, u);
}

// ---------------- CSR build ----------------
__global__ void count_kernel(const int* __restrict__ dst, int* __restrict__ deg,
                             int* __restrict__ epos) {
    int e = blockIdx.x * 256 + threadIdx.x;
    if (e < NEDGES) epos[e] = atomicAdd(&deg[dst[e]], 1);
}

__global__ __launch_bounds__(256) void bsum_kernel(const int* __restrict__ deg,
                                                   int* __restrict__ bsum) {
    __shared__ int red[256];
    int i = blockIdx.x * 256 + threadIdx.x;
    red[threadIdx.x] = (i < NNODES) ? deg[i] : 0;
    __syncthreads();
    for (int off = 128; off; off >>= 1) {
        if (threadIdx.x < off) red[threadIdx.x] += red[threadIdx.x + off];
        __syncthreads();
    }
    if (threadIdx.x == 0) bsum[blockIdx.x] = red[0];
}

__global__ __launch_bounds__(256) void bscan_kernel(const int* __restrict__ bsum,
                                                    int* __restrict__ bofs) {
    __shared__ int s[256];
    int t = threadIdx.x;
    int v = (t < 196) ? bsum[t] : 0;
    s[t] = v;
    __syncthreads();
    for (int off = 1; off < 256; off <<= 1) {
        int u = (t >= off) ? s[t - off] : 0;
        __syncthreads();
        s[t] += u;
        __syncthreads();
    }
    if (t < 196) bofs[t] = s[t] - v;  // exclusive
}

__global__ __launch_bounds__(256) void emit_kernel(
    const int* __restrict__ deg, const int* __restrict__ bofs,
    int* __restrict__ row_ptr, float* __restrict__ norm) {
    __shared__ int s[256];
    int t = threadIdx.x;
    int i = blockIdx.x * 256 + t;
    int v = (i < NNODES) ? deg[i] : 0;
    s[t] = v;
    __syncthreads();
    for (int off = 1; off < 256; off <<= 1) {
        int u = (t >= off) ? s[t - off] : 0;
        __syncthreads();
        s[t] += u;
        __syncthreads();
    }
    int excl = s[t] - v + bofs[blockIdx.x];
    if (i < NNODES) {
        row_ptr[i] = excl;
        norm[i] = rsqrtf(1.0f + (float)v);
    }
    if (i == NNODES - 1) row_ptr[NNODES] = NEDGES;
}

__global__ void fill_kernel(const int* __restrict__ src, const int* __restrict__ dst,
                            const int* __restrict__ epos, const int* __restrict__ row_ptr,
                            int* __restrict__ sorted_src) {
    int e = blockIdx.x * 256 + threadIdx.x;
    if (e < NEDGES) sorted_src[row_ptr[dst[e]] + epos[e]] = src[e];
}

// ---------------- weight prep ----------------
// bf16 hi/lo (wT): w_in slot 0, w1[m] slot 1+m, w_out slot 7 (64 rows).
// f16 single (w2f): w2[m] at m*16384, layout [n][128].
__global__ __launch_bounds__(256) void prep_w_kernel(
    const float* __restrict__ w_in, const float* __restrict__ w1,
    const float* __restrict__ w2, const float* __restrict__ w_out,
    unsigned short* __restrict__ wT, _Float16* __restrict__ w2f) {
    int idx = blockIdx.x * 256 + threadIdx.x;  // total 221184 = 864*256
    if (idx < 16384 + 98304) {
        const float* W;
        unsigned short* o;
        int e;
        if (idx < 16384) {
            W = w_in; o = wT; e = idx;
        } else {
            int j = idx - 16384; int m = j >> 14; e = j & 16383;
            W = w1 + ((size_t)m << 14); o = wT + (size_t)(1 + m) * 32768;
        }
        int k = e >> 7, n = e & 127;
        float v = W[e];
        unsigned short h = f2bf(v);
        o[(size_t)n * 256 + k] = h;
        o[(size_t)n * 256 + 128 + k] = f2bf(v - bf2f(h));
    } else if (idx < 16384 + 196608) {
        int j = idx - 16384 - 98304; int m = j >> 14; int e = j & 16383;
        int k = e >> 7, n = e & 127;
        w2f[(size_t)m * 16384 + n * 128 + k] = (_Float16)w2[((size_t)m << 14) + e];
    } else {
        int e = idx - 212992;  // w_out: 8192 elements
        int k = e >> 6, n = e & 63;
        float v = w_out[e];
        unsigned short h = f2bf(v);
        unsigned short* o = wT + (size_t)7 * 32768;
        o[(size_t)n * 256 + k] = h;
        o[(size_t)n * 256 + 128 + k] = f2bf(v - bf2f(h));
    }
}

// ---------------- x split (input layer only) ----------------
__global__ __launch_bounds__(256) void split_x_kernel(
    const float* __restrict__ x, unsigned short* __restrict__ xc) {
    int gid = blockIdx.x * 256 + threadIdx.x;
    int row = gid >> 6;
    int kk = (gid & 63) * 2;
    float2 v = {0.f, 0.f};
    if (row < NNODES) v = *(const float2*)(x + (size_t)row * 128 + kk);
    unsigned short h0 = f2bf(v.x), h1 = f2bf(v.y);
    unsigned short l0 = f2bf(v.x - bf2f(h0)), l1 = f2bf(v.y - bf2f(h1));
    *(unsigned int*)(xc + (size_t)row * 256 + kk) =
        (unsigned int)h0 | ((unsigned int)h1 << 16);
    *(unsigned int*)(xc + (size_t)row * 256 + 128 + kk) =
        (unsigned int)l0 | ((unsigned int)l1 << 16);
}

// ---------------- bf16 hi/lo streaming MFMA GEMM ----------------
template <int NCOLS>
__global__ __launch_bounds__(GEMM_BLK) void gemm_bf_kernel(
    const unsigned short* __restrict__ xc, const unsigned short* __restrict__ wT,
    const float* __restrict__ norm, _Float16* __restrict__ y) {
    __shared__ unsigned short Blds[NCOLS * 256];
    const int t = threadIdx.x;
    const int wave = t >> 6, lane = t & 63, quad = lane >> 4, l16 = lane & 15;

    constexpr int NCH = NCOLS * 32;  // 16B chunks total
#pragma unroll
    for (int i = 0; i < NCH / GEMM_BLK; ++i) {
        int C = i * GEMM_BLK + t;
        int n = C >> 5, c = C & 31;
        const unsigned short* gp = wT + ((size_t)n << 8) + ((c ^ (n & 7)) << 3);
        unsigned short* lp = Blds + ((size_t)C << 3);
        __builtin_amdgcn_global_load_lds(
            (const __attribute__((address_space(1))) void*)gp,
            (__attribute__((address_space(3))) void*)lp, 16, 0, 0);
    }
    __syncthreads();

    const int wid = blockIdx.x * (GEMM_BLK / 64) + wave;
    const int sw = l16 & 7;
    const int rb0 = wid * 16;

    short8 a0[8];
    const unsigned short* ap0 = xc + ((size_t)(rb0 + l16) << 8) + quad * 8;
#pragma unroll
    for (int ck = 0; ck < 8; ++ck) a0[ck] = *(const short8*)(ap0 + ck * 32);

    float nm0[4];
#pragma unroll
    for (int r = 0; r < 4; ++r) {
        int r0 = rb0 + quad * 4 + r;
        nm0[r] = norm[r0 < NNODES ? r0 : 0];
    }

#pragma unroll
    for (int nt = 0; nt < NCOLS / 16; ++nt) {
        const unsigned short* bp = Blds + ((size_t)(nt * 16 + l16) << 8);
        short8 bh[4], bl[4];
#pragma unroll
        for (int ck = 0; ck < 4; ++ck) {
            bh[ck] = *(const short8*)(bp + (((ck * 4 + quad) ^ sw) << 3));
            bl[ck] = *(const short8*)(bp + (((16 + ck * 4 + quad) ^ sw) << 3));
        }
        f32x4 ac0 = (f32x4){0.f, 0.f, 0.f, 0.f};
#pragma unroll
        for (int ck = 0; ck < 4; ++ck) {
            ac0 = __builtin_amdgcn_mfma_f32_16x16x32_bf16(a0[ck], bh[ck], ac0, 0, 0, 0);
            ac0 = __builtin_amdgcn_mfma_f32_16x16x32_bf16(a0[ck], bl[ck], ac0, 0, 0, 0);
            ac0 = __builtin_amdgcn_mfma_f32_16x16x32_bf16(a0[4 + ck], bh[ck], ac0, 0, 0, 0);
        }
        int col = nt * 16 + l16;
#pragma unroll
        for (int r = 0; r < 4; ++r) {
            int r0 = rb0 + quad * 4 + r;
            if (r0 < NNODES) y[(size_t)r0 * NCOLS + col] = (_Float16)(ac0[r] * nm0[r]);
        }
    }
}

// -------- FUSED gather+finalize+f16 GEMM (replaces gather<0,OUT16> + gemm_f16)
// Each wave gathers & finalizes its own 16 A-rows (4 batches of the 4-node /
// 16-lane scheme), writes them to a private 4KB LDS region (wave-local, no
// barrier needed), then runs the MFMA phase with A-frags from LDS.
// Eliminates the h16 global round-trip (write+read, 25.6 MB/block).
__global__ __launch_bounds__(GEMM_BLK) void fgg_f16_kernel(
    const _Float16* __restrict__ y, const int* __restrict__ row_ptr,
    const int* __restrict__ sorted_src, const float* __restrict__ norm,
    const float* __restrict__ bias, const _Float16* __restrict__ wf,
    _Float16* __restrict__ yout) {
    __shared__ _Float16 Blds[128 * 128];          // 32 KB
    __shared__ _Float16 Alds[8 * 16 * 128];       // 32 KB, 4KB per wave
    const int t = threadIdx.x;
    const int wave = t >> 6, lane = t & 63, quad = lane >> 4, l16 = lane & 15;

    // ---- B stage (issued first; drained by the barrier below) ----
#pragma unroll
    for (int i = 0; i < 2048 / GEMM_BLK; ++i) {
        int C = i * GEMM_BLK + t;
        int n = C >> 4, c = C & 15;
        const _Float16* gp = wf + ((size_t)n << 7) + ((c ^ (n & 7)) << 3);
        _Float16* lp = Blds + ((size_t)C << 3);
        __builtin_amdgcn_global_load_lds(
            (const __attribute__((address_space(1))) void*)gp,
            (__attribute__((address_space(3))) void*)lp, 16, 0, 0);
    }

    const int wid = blockIdx.x * (GEMM_BLK / 64) + wave;
    const int rb0 = wid * 16;
    _Float16* Aw = Alds + (size_t)wave * 2048;
    const int g = quad, j = l16;

    // ---- gather phase: 4 batches x 4 nodes/wave, 16 lanes per node ----
    for (int tb = 0; tb < 4; ++tb) {
        const int n = rb0 + tb * 4 + g;
        const bool valid = n < NNODES;
        const int beg = valid ? row_ptr[n] : 0;
        const int dg = valid ? (row_ptr[n + 1] - beg) : 0;
        int dmax = dg;
        dmax = max(dmax, __shfl_xor(dmax, 16));
        dmax = max(dmax, __shfl_xor(dmax, 32));

        f32x8 acc = (f32x8){0.f, 0.f, 0.f, 0.f, 0.f, 0.f, 0.f, 0.f};
        for (int i = 0; i < dmax; i += 8) {
            int sarr[8];
#pragma unroll
            for (int u = 0; u < 8; ++u)
                sarr[u] = (i + u < dg) ? sorted_src[beg + i + u] : -1;
            half8 h[8];
#pragma unroll
            for (int u = 0; u < 8; ++u)
                if (sarr[u] >= 0)
                    h[u] = *(const half8*)(y + ((size_t)sarr[u] << 7) + j * 8);
#pragma unroll
            for (int u = 0; u < 8; ++u)
                if (sarr[u] >= 0) acc += __builtin_convertvector(h[u], f32x8);
        }

        half8 o;
        if (valid) {
            const half8 sh = *(const half8*)(y + ((size_t)n << 7) + j * 8);
            const f32x4 b0 = *(const f32x4*)(bias + j * 8);
            const f32x4 b1 = *(const f32x4*)(bias + j * 8 + 4);
            const float bb[8] = {b0[0], b0[1], b0[2], b0[3], b1[0], b1[1], b1[2], b1[3]};
            const float nm = norm[n];
#pragma unroll
            for (int c = 0; c < 8; ++c) {
                float v = (acc[c] + (float)sh[c]) * nm + bb[c];
                v = v >= 0.f ? v : 0.01f * v;
                o[c] = (_Float16)v;
            }
        } else {
#pragma unroll
            for (int c = 0; c < 8; ++c) o[c] = (_Float16)0.f;
        }
        *(half8*)(Aw + (size_t)(tb * 4 + g) * 128 + j * 8) = o;
    }
    __syncthreads();  // B staged; A (wave-local) ordered by lgkmcnt deps

    // ---- MFMA phase (A from wave-local LDS, B from block LDS) ----
    const int sw = l16 & 7;
    half8 a0[4];
#pragma unroll
    for (int ck = 0; ck < 4; ++ck)
        a0[ck] = *(const half8*)(Aw + (size_t)l16 * 128 + ck * 32 + quad * 8);

    float nm0[4];
#pragma unroll
    for (int r = 0; r < 4; ++r) {
        int r0 = rb0 + quad * 4 + r;
        nm0[r] = norm[r0 < NNODES ? r0 : 0];
    }

#pragma unroll
    for (int nt = 0; nt < 8; ++nt) {
        const _Float16* bp = Blds + ((size_t)(nt * 16 + l16) << 7);
        half8 b[4];
#pragma unroll
        for (int ck = 0; ck < 4; ++ck)
            b[ck] = *(const half8*)(bp + (((ck * 4 + quad) ^ sw) << 3));
        f32x4 ac0 = (f32x4){0.f, 0.f, 0.f, 0.f};
#pragma unroll
        for (int ck = 0; ck < 4; ++ck)
            ac0 = __builtin_amdgcn_mfma_f32_16x16x32_f16(a0[ck], b[ck], ac0, 0, 0, 0);
        int col = nt * 16 + l16;
#pragma unroll
        for (int r = 0; r < 4; ++r) {
            int r0 = rb0 + quad * 4 + r;
            if (r0 < NNODES) yout[(size_t)r0 * 128 + col] = (_Float16)(ac0[r] * nm0[r]);
        }
    }
}

// ---------------- fused gather + finalize (F=128, fp16 y) ----------------
template <int MODE, bool WOUT, bool OUT16>
__global__ __launch_bounds__(256) void gather_fin128(
    const _Float16* __restrict__ y, const int* __restrict__ row_ptr,
    const int* __restrict__ sorted_src, const float* __restrict__ norm,
    const float* __restrict__ bias, const unsigned short* __restrict__ xcres,
    float* __restrict__ out, unsigned short* __restrict__ xcout,
    _Float16* __restrict__ h16) {
    const int wave = threadIdx.x >> 6;
    const int lane = threadIdx.x & 63;
    const int g = lane >> 4, j = lane & 15;
    const int n = blockIdx.x * 16 + wave * 4 + g;
    const int beg = row_ptr[n];
    const int deg = row_ptr[n + 1] - beg;
    int dmax = deg;
    dmax = max(dmax, __shfl_xor(dmax, 16));
    dmax = max(dmax, __shfl_xor(dmax, 32));

    f32x8 acc = (f32x8){0.f, 0.f, 0.f, 0.f, 0.f, 0.f, 0.f, 0.f};

    for (int i = 0; i < dmax; i += 8) {
        int sarr[8];
#pragma unroll
        for (int u = 0; u < 8; ++u)
            sarr[u] = (i + u < deg) ? sorted_src[beg + i + u] : -1;
        half8 h[8];
#pragma unroll
        for (int u = 0; u < 8; ++u)
            if (sarr[u] >= 0)
                h[u] = *(const half8*)(y + ((size_t)sarr[u] << 7) + j * 8);
#pragma unroll
        for (int u = 0; u < 8; ++u)
            if (sarr[u] >= 0) acc += __builtin_convertvector(h[u], f32x8);
    }

    const half8 sh = *(const half8*)(y + ((size_t)n << 7) + j * 8);
    const f32x4 b0 = *(const f32x4*)(bias + j * 8);
    const f32x4 b1 = *(const f32x4*)(bias + j * 8 + 4);
    const float bb[8] = {b0[0], b0[1], b0[2], b0[3], b1[0], b1[1], b1[2], b1[3]};
    const float nm = norm[n];
    float v[8];
#pragma unroll
    for (int c = 0; c < 8; ++c) {
        float t = (acc[c] + (float)sh[c]) * nm + bb[c];
        v[c] = t >= 0.f ? t : 0.01f * t;
    }
    if (MODE == 1) {
        short8 hw = __builtin_nontemporal_load(
            (const short8*)(xcres + ((size_t)n << 8) + j * 8));
        short8 lw = __builtin_nontemporal_load(
            (const short8*)(xcres + ((size_t)n << 8) + 128 + j * 8));
#pragma unroll
        for (int c = 0; c < 8; ++c) {
            float xr = bf2f((unsigned short)hw[c]) + bf2f((unsigned short)lw[c]);
            v[c] = (xr + v[c]) * 0.5f;
        }
    }
    if (WOUT) {
        f32x4 o0 = (f32x4){v[0], v[1], v[2], v[3]};
        f32x4 o1 = (f32x4){v[4], v[5], v[6], v[7]};
        __builtin_nontemporal_store(o0, (f32x4*)(out + ((size_t)n << 7) + j * 8));
        __builtin_nontemporal_store(o1, (f32x4*)(out + ((size_t)n << 7) + j * 8 + 4));
    }
    if (OUT16) {
        half8 o;
#pragma unroll
        for (int c = 0; c < 8; ++c) o[c] = (_Float16)v[c];
        *(half8*)(h16 + ((size_t)n << 7) + j * 8) = o;
    } else {
        short8 hi, lo;
#pragma unroll
        for (int c = 0; c < 8; ++c) {
            unsigned short hv = f2bf(v[c]);
            hi[c] = (short)hv;
            lo[c] = (short)f2bf(v[c] - bf2f(hv));
        }
        *(short8*)(xcout + ((size_t)n << 8) + j * 8) = hi;
        *(short8*)(xcout + ((size_t)n << 8) + 128 + j * 8) = lo;
    }
}

// ---------------- final gather (F=64, identity, fp16 y) ----------------
__global__ __launch_bounds__(256) void gather_fin64(
    const _Float16* __restrict__ y, const int* __restrict__ row_ptr,
    const int* __restrict__ sorted_src, const float* __restrict__ norm,
    const float* __restrict__ bias, float* __restrict__ out) {
    const int wave = threadIdx.x >> 6;
    const int lane = threadIdx.x & 63;
    const int g = lane >> 4, j = lane & 15;
    const int n = blockIdx.x * 16 + wave * 4 + g;
    const int beg = row_ptr[n];
    const int deg = row_ptr[n + 1] - beg;
    int dmax = deg;
    dmax = max(dmax, __shfl_xor(dmax, 16));
    dmax = max(dmax, __shfl_xor(dmax, 32));

    f32x4 acc = (f32x4){0.f, 0.f, 0.f, 0.f};
    for (int i = 0; i < dmax; i += 8) {
        int sarr[8];
#pragma unroll
        for (int u = 0; u < 8; ++u)
            sarr[u] = (i + u < deg) ? sorted_src[beg + i + u] : -1;
        half4 h[8];
#pragma unroll
        for (int u = 0; u < 8; ++u)
            if (sarr[u] >= 0)
                h[u] = *(const half4*)(y + ((size_t)sarr[u] << 6) + j * 4);
#pragma unroll
        for (int u = 0; u < 8; ++u)
            if (sarr[u] >= 0) acc += __builtin_convertvector(h[u], f32x4);
    }

    const half4 sh = *(const half4*)(y + ((size_t)n << 6) + j * 4);
    const f32x4 b = *(const f32x4*)(bias + j * 4);
    const float nm = norm[n];
    f32x4 o;
    o[0] = (acc[0] + (float)sh[0]) * nm + b[0];
    o[1] = (acc[1] + (float)sh[1]) * nm + b[1];
    o[2] = (acc[2] + (float)sh[2]) * nm + b[2];
    o[3] = (acc[3] + (float)sh[3]) * nm + b[3];
    __builtin_nontemporal_store(o, (f32x4*)(out + ((size_t)n << 6) + j * 4));
}

extern "C" void kernel_launch(void* const* d_in, const int* in_sizes, int n_in,
                              void* d_out, int out_size, void* d_ws, size_t ws_size,
                              hipStream_t stream) {
    const float* inputs = (const float*)d_in[0];
    const int* edges = (const int*)d_in[1];
    const int* src = edges;
    const int* dst = edges + NEDGES;
    const float* w_in  = (const float*)d_in[2];
    const float* b_in  = (const float*)d_in[3];
    const float* w1    = (const float*)d_in[4];
    const float* b1    = (const float*)d_in[5];
    const float* w2    = (const float*)d_in[6];
    const float* b2    = (const float*)d_in[7];
    const float* w_out = (const float*)d_in[8];
    const float* b_out = (const float*)d_in[9];

    float* out  = (float*)d_out;
    float* xout = out;                                // [N, 64]
    float* x    = out + (size_t)NNODES * OUTDIM;      // [N, 128] fp32 x (final only)

    char* p = (char*)d_ws;
    auto alloc = [&](size_t bytes) {
        char* r = p;
        p += (bytes + 63) & ~(size_t)63;
        return r;
    };
    int* deg        = (int*)alloc(NNODES * 4);
    int* epos       = (int*)alloc(NEDGES * 4);
    int* row_ptr    = (int*)alloc((NNODES + 1) * 4);
    int* bsum       = (int*)alloc(256 * 4);
    int* bofs       = (int*)alloc(256 * 4);
    int* sorted_src = (int*)alloc(NEDGES * 4);
    float* normb    = (float*)alloc(NNODES * 4);
    unsigned short* wT = (unsigned short*)alloc((size_t)245760 * 2);  // 7*32768+16384
    _Float16* w2f   = (_Float16*)alloc((size_t)6 * 16384 * 2);
    unsigned short* xc_x = (unsigned short*)alloc((size_t)NPAD * 256 * 2);
    unsigned short* xc_in = (unsigned short*)alloc((size_t)NPAD * 256 * 2);
    _Float16* y2    = (_Float16*)alloc((size_t)NPAD * 128 * 2);   // fused GEMM out
    _Float16* y     = (_Float16*)alloc((size_t)NNODES * HDIM * 2);

    // ---- CSR + norm + weight prep ----
    hipMemsetAsync(deg, 0, NNODES * sizeof(int), stream);
    count_kernel<<<(NEDGES + 255) / 256, 256, 0, stream>>>(dst, deg, epos);
    bsum_kernel<<<196, 256, 0, stream>>>(deg, bsum);
    bscan_kernel<<<1, 256, 0, stream>>>(bsum, bofs);
    emit_kernel<<<196, 256, 0, stream>>>(deg, bofs, row_ptr, normb);
    fill_kernel<<<(NEDGES + 255) / 256, 256, 0, stream>>>(src, dst, epos, row_ptr, sorted_src);
    prep_w_kernel<<<864, 256, 0, stream>>>(w_in, w1, w2, w_out, wT, w2f);

    // input layer
    split_x_kernel<<<(NPAD * 64) / 256, 256, 0, stream>>>(inputs, xc_in);
    gemm_bf_kernel<128><<<GEMM_GRID, GEMM_BLK, 0, stream>>>(xc_in, wT, normb, y);
    gather_fin128<0, false, false><<<NNODES / 16, 256, 0, stream>>>(
        y, row_ptr, sorted_src, normb, b_in, nullptr, nullptr, xc_x, nullptr);

    // 6 residual blocks
    for (int i = 0; i < 6; ++i) {
        gemm_bf_kernel<128><<<GEMM_GRID, GEMM_BLK, 0, stream>>>(
            xc_x, wT + (size_t)(1 + i) * 32768, normb, y);
        fgg_f16_kernel<<<GEMM_GRID, GEMM_BLK, 0, stream>>>(
            y, row_ptr, sorted_src, normb, b1 + i * HDIM,
            w2f + (size_t)i * 16384, y2);
        if (i < 5)
            gather_fin128<1, false, false><<<NNODES / 16, 256, 0, stream>>>(
                y2, row_ptr, sorted_src, normb, b2 + i * HDIM, xc_x, nullptr, xc_x, nullptr);
        else
            gather_fin128<1, true, false><<<NNODES / 16, 256, 0, stream>>>(
                y2, row_ptr, sorted_src, normb, b2 + i * HDIM, xc_x, x, xc_x, nullptr);
    }

    // output layer (H -> 64, identity)
    gemm_bf_kernel<64><<<GEMM_GRID, GEMM_BLK, 0, stream>>>(
        xc_x, wT + (size_t)7 * 32768, normb, y);
    gather_fin64<<<NNODES / 16, 256, 0, stream>>>(
        y, row_ptr, sorted_src, normb, b_out, xout);
}